// Round 5
// baseline (314.895 us; speedup 1.0000x reference)
//
#include <hip/hip_runtime.h>
#include <hip/hip_bf16.h>
#include <cstdint>

// ---- problem constants ----
#define BB 32
#define NN 1024
#define CC 768
#define MM 64
#define HH 12
#define DD 64

typedef float f4v __attribute__((ext_vector_type(4)));
typedef __bf16 bf8 __attribute__((ext_vector_type(8)));
typedef __bf16 bf4 __attribute__((ext_vector_type(4)));

__device__ __forceinline__ f4v mfma16(bf8 a, bf8 b, f4v c) {
    return __builtin_amdgcn_mfma_f32_16x16x32_bf16(a, b, c, 0, 0, 0);
}
__device__ __forceinline__ __bf16 f2bf(float f) { return (__bf16)f; }

__device__ __forceinline__ void gl2lds16(const void* g, void* lds) {
    __builtin_amdgcn_global_load_lds((const __attribute__((address_space(1))) void*)g,
                                     (__attribute__((address_space(3))) void*)lds, 16, 0, 0);
}

// ---------- all weight fp32 -> bf16 in ONE launch ----------
__global__ __launch_bounds__(256) void k_cvtW(
        const float* __restrict__ Wc, const float* __restrict__ Wq,
        const float* __restrict__ Wk, const float* __restrict__ Wv,
        const float* __restrict__ Wp,
        __bf16* __restrict__ wc, __bf16* __restrict__ wq,
        __bf16* __restrict__ wk, __bf16* __restrict__ wv,
        __bf16* __restrict__ wp) {
    const float* in; __bf16* out; int n4;
    switch (blockIdx.y) {
        case 0: in = Wc; out = wc; n4 = MM * CC / 4; break;
        case 1: in = Wq; out = wq; n4 = CC * CC / 4; break;
        case 2: in = Wk; out = wk; n4 = CC * CC / 4; break;
        case 3: in = Wv; out = wv; n4 = CC * CC / 4; break;
        default: in = Wp; out = wp; n4 = CC * CC / 4; break;
    }
    int i = blockIdx.x * 256 + threadIdx.x;
    if (i < n4) {
        float4 v = *(const float4*)&in[i * 4];
        bf4 o; o[0] = f2bf(v.x); o[1] = f2bf(v.y); o[2] = f2bf(v.z); o[3] = f2bf(v.w);
        *(bf4*)&out[i * 4] = o;
    }
}

// ---------- K0: x -> xb (streamed, no LDS) AND xt (b,c,n) via padded LDS transpose ----------
// xb: converted in regs, stored directly (coalesced 8B/lane).
// xt: bf16 written to tileT[c][n] with pad 66 -> phase-1 scalar writes are 2-way banked
//     (stride 4*66 el = 528 B -> bank step 4), phase-2 reads are contiguous b128.
__global__ __launch_bounds__(256) void k_cvtx(const float* __restrict__ x,
        __bf16* __restrict__ xb, __bf16* __restrict__ xt) {
    int c0 = blockIdx.x * 64, n0 = blockIdx.y * 64, b = blockIdx.z;
    __shared__ __align__(16) __bf16 tileT[64 * 66];
    int t = threadIdx.x;
#pragma unroll
    for (int i = 0; i < 4; i++) {
        int idx = t + 256 * i, r = idx >> 4, cq = idx & 15;
        float4 v = *(const float4*)&x[((size_t)(b * NN + n0 + r)) * CC + c0 + cq * 4];
        float vv[4] = {v.x, v.y, v.z, v.w};
        bf4 o;
#pragma unroll
        for (int j = 0; j < 4; j++) {
            __bf16 bv = f2bf(vv[j]);
            o[j] = bv;
            tileT[(cq * 4 + j) * 66 + r] = bv;
        }
        *(bf4*)&xb[((size_t)(b * NN + n0 + r)) * CC + c0 + cq * 4] = o;
    }
    __syncthreads();
#pragma unroll
    for (int i = 0; i < 2; i++) {
        int idx = t + 256 * i, c = idx >> 3, ch = idx & 7;
        bf8 v2 = *(const bf8*)&tileT[c * 66 + ch * 8];
        *(bf8*)&xt[((size_t)(b * CC + c0 + c)) * NN + n0 + ch * 8] = v2;
    }
}

// ---------- K1: c_bmn[b,m,n] = sigmoid(x@Wc^T + bc)/N   (LDS-free) ----------
__global__ __launch_bounds__(256) void k_cluster(const __bf16* __restrict__ xb,
        const __bf16* __restrict__ Wc, const float* __restrict__ bc,
        __bf16* __restrict__ cbmn) {
    int n0 = blockIdx.x * 128, b = blockIdx.y;
    int t = threadIdx.x, w = t >> 6, l = t & 63, quad = l >> 4, l16 = l & 15;
    f4v acc[2][4];
#pragma unroll
    for (int i = 0; i < 2; i++) for (int j = 0; j < 4; j++) acc[i][j] = (f4v)0.0f;
    for (int k0 = 0; k0 < CC; k0 += 32) {
        bf8 afr[2], bfr[4];
#pragma unroll
        for (int sr = 0; sr < 2; sr++)
            afr[sr] = *(const bf8*)&xb[((size_t)(b * NN + n0 + w * 32 + sr * 16 + l16)) * CC + k0 + quad * 8];
#pragma unroll
        for (int sc = 0; sc < 4; sc++)
            bfr[sc] = *(const bf8*)&Wc[(size_t)(sc * 16 + l16) * CC + k0 + quad * 8];
#pragma unroll
        for (int sr = 0; sr < 2; sr++)
#pragma unroll
            for (int sc = 0; sc < 4; sc++)
                acc[sr][sc] = mfma16(afr[sr], bfr[sc], acc[sr][sc]);
    }
#pragma unroll
    for (int sr = 0; sr < 2; sr++)
#pragma unroll
        for (int sc = 0; sc < 4; sc++) {
            int m = sc * 16 + l16;
            float bias = bc[m];
            bf4 p;
#pragma unroll
            for (int r = 0; r < 4; r++) {
                float val = acc[sr][sc][r] + bias;
                val = 1.0f / (1.0f + __expf(-val));
                p[r] = f2bf(val * (1.0f / 1024.0f));
            }
            *(bf4*)&cbmn[((size_t)(b * MM + m)) * NN + n0 + w * 32 + sr * 16 + quad * 4] = p;
        }
}

// ---------- K2: z[b,m,c] = sum_n c_bmn[b,m,n] * xt[b,c,n]   (LDS-free, fp32 out) ----------
__global__ __launch_bounds__(256) void k_z(const __bf16* __restrict__ cbmn,
        const __bf16* __restrict__ xt, float* __restrict__ z) {
    int c0 = blockIdx.x * 64, b = blockIdx.y;
    int t = threadIdx.x, w = t >> 6, l = t & 63, quad = l >> 4, l16 = l & 15;
    f4v acc[4];
#pragma unroll
    for (int j = 0; j < 4; j++) acc[j] = (f4v)0.0f;
    for (int n0 = 0; n0 < NN; n0 += 32) {
        bf8 afr = *(const bf8*)&cbmn[((size_t)(b * MM + w * 16 + l16)) * NN + n0 + quad * 8];
#pragma unroll
        for (int sc = 0; sc < 4; sc++) {
            bf8 bfr = *(const bf8*)&xt[((size_t)(b * CC + c0 + sc * 16 + l16)) * NN + n0 + quad * 8];
            acc[sc] = mfma16(afr, bfr, acc[sc]);
        }
    }
#pragma unroll
    for (int sc = 0; sc < 4; sc++) {
        int cc = c0 + sc * 16 + l16;
#pragma unroll
        for (int r = 0; r < 4; r++) {
            int m = w * 16 + quad * 4 + r;
            z[((size_t)(b * MM + m)) * CC + cc] = acc[sc][r];
        }
    }
}

// ---------- K2b: L2-normalize rows of z, write bf16 ----------
__global__ __launch_bounds__(256) void k_znorm(const float* __restrict__ z, __bf16* __restrict__ zb) {
    int w = threadIdx.x >> 6, l = threadIdx.x & 63;
    int row = blockIdx.x * 4 + w;
    const float* zr = &z[(size_t)row * CC];
    float v[12]; float ss = 0.f;
#pragma unroll
    for (int i = 0; i < 12; i++) { v[i] = zr[l + i * 64]; ss += v[i] * v[i]; }
#pragma unroll
    for (int off = 32; off; off >>= 1) ss += __shfl_xor(ss, off);
    float s = 1.0f / fmaxf(sqrtf(ss), 1e-12f);
    __bf16* zo = &zb[(size_t)row * CC];
#pragma unroll
    for (int i = 0; i < 12; i++) zo[l + i * 64] = f2bf(v[i] * s);
}

// ---------- K3: k = z@Wk^T+bk -> (b,h,m,d); v = z@Wv^T+bv -> TRANSPOSED (b,h,d,m) ----------
__global__ __launch_bounds__(256) void k_kv(const __bf16* __restrict__ zb,
        const __bf16* __restrict__ Wk, const float* __restrict__ bk,
        const __bf16* __restrict__ Wv, const float* __restrict__ bv,
        __bf16* __restrict__ kout, __bf16* __restrict__ vtout) {
    int ct = blockIdx.x, b = blockIdx.y, which = blockIdx.z;
    const __bf16* W = which ? Wv : Wk;
    const float* bias = which ? bv : bk;
    int t = threadIdx.x, w = t >> 6, l = t & 63, quad = l >> 4, l16 = l & 15;
    f4v acc[4][2];
#pragma unroll
    for (int i = 0; i < 4; i++) for (int j = 0; j < 2; j++) acc[i][j] = (f4v)0.0f;
    for (int k0 = 0; k0 < CC; k0 += 32) {
        bf8 afr[4], bfr[2];
#pragma unroll
        for (int sr = 0; sr < 4; sr++)
            afr[sr] = *(const bf8*)&zb[((size_t)(b * MM + sr * 16 + l16)) * CC + k0 + quad * 8];
#pragma unroll
        for (int sc = 0; sc < 2; sc++)
            bfr[sc] = *(const bf8*)&W[((size_t)(ct * 128 + w * 32 + sc * 16 + l16)) * CC + k0 + quad * 8];
#pragma unroll
        for (int sr = 0; sr < 4; sr++)
#pragma unroll
            for (int sc = 0; sc < 2; sc++)
                acc[sr][sc] = mfma16(afr[sr], bfr[sc], acc[sr][sc]);
    }
#pragma unroll
    for (int sr = 0; sr < 4; sr++)
#pragma unroll
        for (int sc = 0; sc < 2; sc++) {
            int col = ct * 128 + w * 32 + sc * 16 + l16;
            float bb = bias[col];
            int h = col >> 6, d = col & 63;
            if (which == 0) {
#pragma unroll
                for (int r = 0; r < 4; r++) {
                    int m = sr * 16 + quad * 4 + r;
                    kout[(((size_t)(b * HH + h)) * MM + m) * DD + d] = f2bf(acc[sr][sc][r] + bb);
                }
            } else {
                bf4 p;
#pragma unroll
                for (int r = 0; r < 4; r++) p[r] = f2bf(acc[sr][sc][r] + bb);
                *(bf4*)&vtout[(((size_t)(b * HH + h)) * DD + d) * MM + sr * 16 + quad * 4] = p;
            }
        }
}

// ======== 128x256 4-wave GEMM: A staged (depth-3, 8KB/buf), B direct-global ========
// Per wave: all 128 A-rows x 64 B-cols = 8x4 16x16 frags -> 12 loads / 32 MFMA.
// A-stage chunk swizzle (both-sides): LDS slot s of row r holds global chunk
// s ^ ((r>>1)&3); read slot = quad ^ ((l16>>1)&3). 2 gl2lds per thread per K-tile.
// Per-iter order: B-loads -> A ds_reads -> sched_barrier -> stage A(kt+2) -> MFMA
// -> vmcnt(2) (A(kt+1) done, A(kt+2) stays in flight) -> barrier. One barrier/K-step;
// compiler's B-waits emit vmcnt(2) (stage is the only younger VM op) -> no drain.
#define STAGE_A(Asrc, buf, kk)                                                        \
    do {                                                                              \
        __bf16* _d = (buf);                                                           \
        int _row = t >> 2, _gkc = (t & 3) ^ ((t >> 3) & 3);                           \
        gl2lds16(&(Asrc)[(arow0 + _row) * CC + (kk) + _gkc * 8], &_d[w * 512]);       \
        gl2lds16(&(Asrc)[(arow0 + 64 + _row) * CC + (kk) + _gkc * 8], &_d[2048 + w * 512]); \
    } while (0)

#define GEMM_KLOOP_BD(Asrc, Bsrc)                                                     \
    STAGE_A(Asrc, smem, 0);                                                           \
    STAGE_A(Asrc, smem + 4096, 32);                                                   \
    asm volatile("s_waitcnt vmcnt(2)" ::: "memory");                                  \
    __builtin_amdgcn_s_barrier();                                                     \
    for (int kt = 0; kt < 24; ++kt) {                                                 \
        int k0 = kt * 32;                                                             \
        const __bf16* As = smem + (kt % 3) * 4096;                                    \
        bf8 bfr[4], afr[8];                                                           \
        _Pragma("unroll")                                                             \
        for (int sc = 0; sc < 4; sc++)                                                \
            bfr[sc] = *(const bf8*)&(Bsrc)[(size_t)(jt * 256 + w * 64 + sc * 16 + l16) * CC + k0 + quad * 8]; \
        _Pragma("unroll")                                                             \
        for (int sr = 0; sr < 8; sr++)                                                \
            afr[sr] = *(const bf8*)&As[(sr * 16 + l16) * 32 + swz * 8];               \
        __builtin_amdgcn_sched_barrier(0);                                            \
        if (kt < 22) STAGE_A(Asrc, smem + ((kt + 2) % 3) * 4096, (kt + 2) * 32);      \
        __builtin_amdgcn_s_setprio(1);                                                \
        _Pragma("unroll")                                                             \
        for (int sr = 0; sr < 8; sr++)                                                \
            _Pragma("unroll")                                                         \
            for (int sc = 0; sc < 4; sc++)                                            \
                acc[sr][sc] = mfma16(afr[sr], bfr[sc], acc[sr][sc]);                  \
        __builtin_amdgcn_s_setprio(0);                                                \
        asm volatile("s_waitcnt vmcnt(2)" ::: "memory");                              \
        __builtin_amdgcn_s_barrier();                                                 \
    }

// ---------- K4: q = xb @ Wq^T + bq -> (b,n,c) bf16 ----------
__global__ __launch_bounds__(256, 2) void k_qproj(const __bf16* __restrict__ xb,
        const __bf16* __restrict__ Wq, const float* __restrict__ bq,
        __bf16* __restrict__ qb) {
    // 768 blocks = 8 XCD x 96 (32 arow-stripes x 3 jt) -> A-stripe L2-local per XCD,
    // B-slice (<=1.2MB) hot in every XCD L2.
    int orig = blockIdx.x;
    int lid = (orig & 7) * 96 + (orig >> 3);
    int jt = lid % 3;
    size_t arow0 = (size_t)(lid / 3) * 128;

    __shared__ __align__(16) __bf16 smem[3 * 4096];    // 24 KB A triple-buffer
    __shared__ __align__(16) __bf16 eb[128 * 72];      // 18 KB epilogue
    int t = threadIdx.x, w = t >> 6, l = t & 63, quad = l >> 4, l16 = l & 15;
    int swz = quad ^ ((l16 >> 1) & 3);
    f4v acc[8][4];
#pragma unroll
    for (int i = 0; i < 8; i++) for (int j = 0; j < 4; j++) acc[i][j] = (f4v)0.0f;

    GEMM_KLOOP_BD(xb, Wq);

    // epilogue: 4 phases; phase p: wave p dumps its 128x64 (pad 72), all store full lines
    for (int p = 0; p < 4; ++p) {
        if (w == p) {
#pragma unroll
            for (int sc = 0; sc < 4; sc++) {
                int col = jt * 256 + p * 64 + sc * 16 + l16;
                float bb = bq[col];
#pragma unroll
                for (int sr = 0; sr < 8; sr++)
#pragma unroll
                    for (int r = 0; r < 4; r++)
                        eb[(sr * 16 + quad * 4 + r) * 72 + sc * 16 + l16] = f2bf(acc[sr][sc][r] + bb);
            }
        }
        __syncthreads();
#pragma unroll
        for (int i = 0; i < 4; i++) {
            int idx = t + 256 * i, row = idx >> 3, ch = idx & 7;
            *(bf8*)&qb[(arow0 + row) * CC + jt * 256 + p * 64 + ch * 8] = *(const bf8*)&eb[row * 72 + ch * 8];
        }
        __syncthreads();
    }
}

// ---------- K5: attention: s=q@k^T, softmax, o=p@v  (full-line o stores via ps) ----------
#define QS 72
__global__ __launch_bounds__(256) void k_attn(const __bf16* __restrict__ qb,
        const __bf16* __restrict__ kb, const __bf16* __restrict__ vt,
        __bf16* __restrict__ ob) {
    int n0 = blockIdx.x * 128, h = blockIdx.y, b = blockIdx.z;
    __shared__ __align__(16) __bf16 ps[128 * QS];
    int t = threadIdx.x, w = t >> 6, l = t & 63, quad = l >> 4, l16 = l & 15;
    size_t bh = (size_t)(b * HH + h);

    f4v sacc[2][4];
#pragma unroll
    for (int i = 0; i < 2; i++) for (int j = 0; j < 4; j++) sacc[i][j] = (f4v)0.0f;
#pragma unroll
    for (int kc = 0; kc < 2; kc++) {
        bf8 afr[2], bfr[4];
#pragma unroll
        for (int sr = 0; sr < 2; sr++)
            afr[sr] = *(const bf8*)&qb[((size_t)(b * NN + n0 + w * 32 + sr * 16 + l16)) * CC + h * 64 + kc * 32 + quad * 8];
#pragma unroll
        for (int sc = 0; sc < 4; sc++)
            bfr[sc] = *(const bf8*)&kb[(bh * MM + sc * 16 + l16) * DD + kc * 32 + quad * 8];
#pragma unroll
        for (int sr = 0; sr < 2; sr++)
#pragma unroll
            for (int sc = 0; sc < 4; sc++)
                sacc[sr][sc] = mfma16(afr[sr], bfr[sc], sacc[sr][sc]);
    }
#pragma unroll
    for (int sr = 0; sr < 2; sr++) {
#pragma unroll
        for (int r = 0; r < 4; r++) {
            float mx = -1e30f;
#pragma unroll
            for (int sc = 0; sc < 4; sc++) mx = fmaxf(mx, sacc[sr][sc][r] * 0.125f);
#pragma unroll
            for (int off = 1; off < 16; off <<= 1) mx = fmaxf(mx, __shfl_xor(mx, off));
            float e[4]; float sum = 0.f;
#pragma unroll
            for (int sc = 0; sc < 4; sc++) { e[sc] = __expf(sacc[sr][sc][r] * 0.125f - mx); sum += e[sc]; }
#pragma unroll
            for (int off = 1; off < 16; off <<= 1) sum += __shfl_xor(sum, off);
            float inv = 1.0f / sum;
            int row = w * 32 + sr * 16 + quad * 4 + r;
#pragma unroll
            for (int sc = 0; sc < 4; sc++) ps[row * QS + sc * 16 + l16] = f2bf(e[sc] * inv);
        }
    }
    f4v oacc[2][4];
#pragma unroll
    for (int i = 0; i < 2; i++) for (int j = 0; j < 4; j++) oacc[i][j] = (f4v)0.0f;
#pragma unroll
    for (int kc = 0; kc < 2; kc++) {
        bf8 afr[2], bfr[4];
#pragma unroll
        for (int sr = 0; sr < 2; sr++)
            afr[sr] = *(const bf8*)&ps[(w * 32 + sr * 16 + l16) * QS + kc * 32 + quad * 8];
#pragma unroll
        for (int sc = 0; sc < 4; sc++)
            bfr[sc] = *(const bf8*)&vt[(bh * DD + sc * 16 + l16) * MM + kc * 32 + quad * 8];
#pragma unroll
        for (int sr = 0; sr < 2; sr++)
#pragma unroll
            for (int sc = 0; sc < 4; sc++)
                oacc[sr][sc] = mfma16(afr[sr], bfr[sc], oacc[sr][sc]);
    }
#pragma unroll
    for (int sr = 0; sr < 2; sr++)
#pragma unroll
        for (int sc = 0; sc < 4; sc++) {
            int row = w * 32 + sr * 16;
#pragma unroll
            for (int r = 0; r < 4; r++)
                ps[(row + quad * 4 + r) * QS + sc * 16 + l16] = f2bf(oacc[sr][sc][r]);
        }
    __syncthreads();
#pragma unroll
    for (int i = 0; i < 4; i++) {
        int idx = t + 256 * i, row = idx >> 3, ch = idx & 7;
        *(bf8*)&ob[((size_t)(b * NN + n0 + row)) * CC + h * 64 + ch * 8] = *(const bf8*)&ps[row * QS + ch * 8];
    }
}

// ---------- K6: out = o @ Wp^T + bp  (fp32 out) ----------
__global__ __launch_bounds__(256, 2) void k_oproj(const __bf16* __restrict__ ob,
        const __bf16* __restrict__ Wp, const float* __restrict__ bp,
        float* __restrict__ out) {
    int orig = blockIdx.x;
    int lid = (orig & 7) * 96 + (orig >> 3);
    int jt = lid % 3;
    size_t arow0 = (size_t)(lid / 3) * 128;

    __shared__ __align__(16) __bf16 smem[3 * 4096];    // 24 KB A triple-buffer
    __shared__ __align__(16) float ebf[128 * 68];      // 34 KB fp32 epilogue
    int t = threadIdx.x, w = t >> 6, l = t & 63, quad = l >> 4, l16 = l & 15;
    int swz = quad ^ ((l16 >> 1) & 3);
    f4v acc[8][4];
#pragma unroll
    for (int i = 0; i < 8; i++) for (int j = 0; j < 4; j++) acc[i][j] = (f4v)0.0f;

    GEMM_KLOOP_BD(ob, Wp);

    for (int p = 0; p < 4; ++p) {
        if (w == p) {
#pragma unroll
            for (int sc = 0; sc < 4; sc++) {
                int col = jt * 256 + p * 64 + sc * 16 + l16;
                float bb = bp[col];
#pragma unroll
                for (int sr = 0; sr < 8; sr++)
#pragma unroll
                    for (int r = 0; r < 4; r++)
                        ebf[(sr * 16 + quad * 4 + r) * 68 + sc * 16 + l16] = acc[sr][sc][r] + bb;
            }
        }
        __syncthreads();
#pragma unroll
        for (int i = 0; i < 8; i++) {
            int idx = t + 256 * i, row = idx >> 4, c4 = idx & 15;
            *(float4*)&out[(arow0 + row) * CC + jt * 256 + p * 64 + c4 * 4] = *(const float4*)&ebf[row * 68 + c4 * 4];
        }
        __syncthreads();
    }
}

extern "C" void kernel_launch(void* const* d_in, const int* in_sizes, int n_in,
                              void* d_out, int out_size, void* d_ws, size_t ws_size,
                              hipStream_t stream) {
    (void)in_sizes; (void)n_in; (void)out_size; (void)ws_size;
    const float* x  = (const float*)d_in[0];
    const float* Wc = (const float*)d_in[1];
    const float* bc = (const float*)d_in[2];
    const float* Wq = (const float*)d_in[3];
    const float* bq = (const float*)d_in[4];
    const float* Wk = (const float*)d_in[5];
    const float* bk = (const float*)d_in[6];
    const float* Wv = (const float*)d_in[7];
    const float* bv = (const float*)d_in[8];
    const float* Wp = (const float*)d_in[9];
    const float* bp = (const float*)d_in[10];
    float* out = (float*)d_out;

    char* ws = (char*)d_ws;
    size_t off = 0;
    auto alloc = [&](size_t bytes) { void* p = ws + off; off = (off + bytes + 255) & ~(size_t)255; return p; };
    __bf16* wc_b = (__bf16*)alloc((size_t)MM * CC * 2);
    __bf16* wq_b = (__bf16*)alloc((size_t)CC * CC * 2);
    __bf16* wk_b = (__bf16*)alloc((size_t)CC * CC * 2);
    __bf16* wv_b = (__bf16*)alloc((size_t)CC * CC * 2);
    __bf16* wp_b = (__bf16*)alloc((size_t)CC * CC * 2);
    __bf16* xb   = (__bf16*)alloc((size_t)BB * NN * CC * 2);
    __bf16* xt_o = (__bf16*)alloc((size_t)BB * NN * CC * 2);  // xt, reused as o
    __bf16* q_b  = (__bf16*)alloc((size_t)BB * NN * CC * 2);
    __bf16* c_bmn= (__bf16*)alloc((size_t)BB * MM * NN * 2);
    float*  z_f  = (float*) alloc((size_t)BB * MM * CC * 4);
    __bf16* z_b  = (__bf16*)alloc((size_t)BB * MM * CC * 2);
    __bf16* k_b  = (__bf16*)alloc((size_t)BB * HH * MM * DD * 2);
    __bf16* v_t  = (__bf16*)alloc((size_t)BB * HH * MM * DD * 2);

    k_cvtW<<<dim3((CC * CC / 4 + 255) / 256, 5), 256, 0, stream>>>(
        Wc, Wq, Wk, Wv, Wp, wc_b, wq_b, wk_b, wv_b, wp_b);

    k_cvtx<<<dim3(CC / 64, NN / 64, BB), 256, 0, stream>>>(x, xb, xt_o);
    k_cluster<<<dim3(NN / 128, BB), 256, 0, stream>>>(xb, wc_b, bc, c_bmn);
    k_z<<<dim3(CC / 64, BB), 256, 0, stream>>>(c_bmn, xt_o, z_f);
    k_znorm<<<(BB * MM) / 4, 256, 0, stream>>>(z_f, z_b);
    k_kv<<<dim3(CC / 128, BB, 2), 256, 0, stream>>>(z_b, wk_b, bk, wv_b, bv, k_b, v_t);
    k_qproj<<<dim3((BB * NN / 128) * 3), 256, 0, stream>>>(xb, wq_b, bq, q_b);
    k_attn<<<dim3(NN / 128, HH, BB), 256, 0, stream>>>(q_b, k_b, v_t, xt_o /* o reuses xt */);
    k_oproj<<<dim3((BB * NN / 128) * 3), 256, 0, stream>>>(xt_o, wp_b, bp, out);
}

// Round 7
// 295.292 us; speedup vs baseline: 1.0664x; 1.0664x over previous
//
#include <hip/hip_runtime.h>
#include <hip/hip_bf16.h>
#include <cstdint>

// ---- problem constants ----
#define BB 32
#define NN 1024
#define CC 768
#define MM 64
#define HH 12
#define DD 64

typedef float f4v __attribute__((ext_vector_type(4)));
typedef __bf16 bf8 __attribute__((ext_vector_type(8)));
typedef __bf16 bf4 __attribute__((ext_vector_type(4)));

__device__ __forceinline__ f4v mfma16(bf8 a, bf8 b, f4v c) {
    return __builtin_amdgcn_mfma_f32_16x16x32_bf16(a, b, c, 0, 0, 0);
}
__device__ __forceinline__ __bf16 f2bf(float f) { return (__bf16)f; }

// ================= fragment-linear layout (lane-order) =================
// frag[tile16][kc32][lane64][8]: element (row, k) lives at
//   tile = row>>4, kc = k>>5, LANE = ((k>>3)&3)*16 + (row&15), e = k&7
//   off  = (tile*NKC + kc)*512 + LANE*8 + e
// A wave's MFMA fragment load = base + l*8 -> ONE coalesced 1KB line, and lane l
// receives exactly its A/B-fragment element (row=l&15, k=(l>>4)*8+e).

// ---------- all weights fp32 -> bf16; Wc/Wq/Wp in FRAG-LINEAR, Wk/Wv row-major ----------
__global__ __launch_bounds__(256) void k_cvtW(
        const float* __restrict__ Wc, const float* __restrict__ Wq,
        const float* __restrict__ Wk, const float* __restrict__ Wv,
        const float* __restrict__ Wp,
        __bf16* __restrict__ wc, __bf16* __restrict__ wq,
        __bf16* __restrict__ wk, __bf16* __restrict__ wv,
        __bf16* __restrict__ wp) {
    const float* in; __bf16* out; int n4; int frag;
    switch (blockIdx.y) {
        case 0: in = Wc; out = wc; n4 = MM * CC / 4; frag = 1; break;
        case 1: in = Wq; out = wq; n4 = CC * CC / 4; frag = 1; break;
        case 2: in = Wk; out = wk; n4 = CC * CC / 4; frag = 0; break;
        case 3: in = Wv; out = wv; n4 = CC * CC / 4; frag = 0; break;
        default: in = Wp; out = wp; n4 = CC * CC / 4; frag = 1; break;
    }
    int i = blockIdx.x * 256 + threadIdx.x;
    if (i < n4) {
        float4 v = *(const float4*)&in[i * 4];
        bf4 o; o[0] = f2bf(v.x); o[1] = f2bf(v.y); o[2] = f2bf(v.z); o[3] = f2bf(v.w);
        if (frag) {
            int lin = i * 4, m = lin / CC, c = lin % CC;
            // lane-order: lane = quad*16 + (m&15), quad = (c>>3)&3
            size_t off = ((size_t)((m >> 4) * 24 + (c >> 5))) * 512
                       + ((((c >> 3) & 3) * 16) + (m & 15)) * 8 + (c & 7);
            *(bf4*)&out[off] = o;
        } else {
            *(bf4*)&out[i * 4] = o;
        }
    }
}

// ---------- K0: x -> xb FRAG-LINEAR bf16  AND  xt (b,c,n) row-major via padded LDS transpose ----------
__global__ __launch_bounds__(256) void k_cvtx(const float* __restrict__ x,
        __bf16* __restrict__ xb, __bf16* __restrict__ xt) {
    int c0 = blockIdx.x * 64, n0 = blockIdx.y * 64, b = blockIdx.z;
    __shared__ __align__(16) __bf16 tileT[64 * 66];
    int t = threadIdx.x;
#pragma unroll
    for (int i = 0; i < 4; i++) {
        int idx = t + 256 * i, r = idx >> 4, cq = idx & 15;
        float4 v = *(const float4*)&x[((size_t)(b * NN + n0 + r)) * CC + c0 + cq * 4];
        float vv[4] = {v.x, v.y, v.z, v.w};
        bf4 o;
#pragma unroll
        for (int j = 0; j < 4; j++) {
            __bf16 bv = f2bf(vv[j]);
            o[j] = bv;
            tileT[(cq * 4 + j) * 66 + r] = bv;
        }
        // frag-linear xb store (lane-order): row n0+r, k-chunk (c0>>5)+(cq>>3),
        // quad = (cq>>1)&3, e0 = (cq&1)*4 -> lane = quad*16 + (r&15)
        int nt = b * 64 + (n0 >> 4) + (r >> 4);
        int kc = (c0 >> 5) + (cq >> 3);
        int quad = (cq >> 1) & 3;
        int e0 = (cq & 1) * 4;
        *(bf4*)&xb[((size_t)(nt * 24 + kc)) * 512 + (quad * 16 + (r & 15)) * 8 + e0] = o;
    }
    __syncthreads();
#pragma unroll
    for (int i = 0; i < 2; i++) {
        int idx = t + 256 * i, c = idx >> 3, ch = idx & 7;
        bf8 v2 = *(const bf8*)&tileT[c * 66 + ch * 8];
        *(bf8*)&xt[((size_t)(b * CC + c0 + c)) * NN + n0 + ch * 8] = v2;
    }
}

// ---------- K1: c_bmn = sigmoid(x@Wc^T + bc)/N  (all operand loads coalesced frag-linear) ----------
__global__ __launch_bounds__(256) void k_cluster(const __bf16* __restrict__ xb,
        const __bf16* __restrict__ Wc, const float* __restrict__ bc,
        __bf16* __restrict__ cbmn) {
    int n0 = blockIdx.x * 128, b = blockIdx.y;
    int t = threadIdx.x, w = t >> 6, l = t & 63, quad = (l >> 4), l16 = l & 15;
    int nt0 = b * 64 + (n0 >> 4);
    f4v acc[2][4];
#pragma unroll
    for (int i = 0; i < 2; i++) for (int j = 0; j < 4; j++) acc[i][j] = (f4v)0.0f;
    for (int kc = 0; kc < 24; kc++) {
        bf8 afr[2], bfr[4];
#pragma unroll
        for (int sr = 0; sr < 2; sr++)
            afr[sr] = *(const bf8*)&xb[((size_t)((nt0 + w * 2 + sr) * 24 + kc)) * 512 + l * 8];
#pragma unroll
        for (int sc = 0; sc < 4; sc++)
            bfr[sc] = *(const bf8*)&Wc[((size_t)(sc * 24 + kc)) * 512 + l * 8];
#pragma unroll
        for (int sr = 0; sr < 2; sr++)
#pragma unroll
            for (int sc = 0; sc < 4; sc++)
                acc[sr][sc] = mfma16(afr[sr], bfr[sc], acc[sr][sc]);
    }
#pragma unroll
    for (int sr = 0; sr < 2; sr++)
#pragma unroll
        for (int sc = 0; sc < 4; sc++) {
            int m = sc * 16 + l16;
            float bias = bc[m];
            bf4 p;
#pragma unroll
            for (int r = 0; r < 4; r++) {
                float val = acc[sr][sc][r] + bias;
                val = 1.0f / (1.0f + __expf(-val));
                p[r] = f2bf(val * (1.0f / 1024.0f));
            }
            *(bf4*)&cbmn[((size_t)(b * MM + m)) * NN + n0 + w * 32 + sr * 16 + quad * 4] = p;
        }
}

// ---------- K2: z[b,m,c] = sum_n c_bmn * xt   (unchanged) ----------
__global__ __launch_bounds__(256) void k_z(const __bf16* __restrict__ cbmn,
        const __bf16* __restrict__ xt, float* __restrict__ z) {
    int c0 = blockIdx.x * 64, b = blockIdx.y;
    int t = threadIdx.x, w = t >> 6, l = t & 63, quad = l >> 4, l16 = l & 15;
    f4v acc[4];
#pragma unroll
    for (int j = 0; j < 4; j++) acc[j] = (f4v)0.0f;
    for (int n0 = 0; n0 < NN; n0 += 32) {
        bf8 afr = *(const bf8*)&cbmn[((size_t)(b * MM + w * 16 + l16)) * NN + n0 + quad * 8];
#pragma unroll
        for (int sc = 0; sc < 4; sc++) {
            bf8 bfr = *(const bf8*)&xt[((size_t)(b * CC + c0 + sc * 16 + l16)) * NN + n0 + quad * 8];
            acc[sc] = mfma16(afr, bfr, acc[sc]);
        }
    }
#pragma unroll
    for (int sc = 0; sc < 4; sc++) {
        int cc = c0 + sc * 16 + l16;
#pragma unroll
        for (int r = 0; r < 4; r++) {
            int m = w * 16 + quad * 4 + r;
            z[((size_t)(b * MM + m)) * CC + cc] = acc[sc][r];
        }
    }
}

// ---------- K2b: L2-normalize rows of z, write bf16 (unchanged) ----------
__global__ __launch_bounds__(256) void k_znorm(const float* __restrict__ z, __bf16* __restrict__ zb) {
    int w = threadIdx.x >> 6, l = threadIdx.x & 63;
    int row = blockIdx.x * 4 + w;
    const float* zr = &z[(size_t)row * CC];
    float v[12]; float ss = 0.f;
#pragma unroll
    for (int i = 0; i < 12; i++) { v[i] = zr[l + i * 64]; ss += v[i] * v[i]; }
#pragma unroll
    for (int off = 32; off; off >>= 1) ss += __shfl_xor(ss, off);
    float s = 1.0f / fmaxf(sqrtf(ss), 1e-12f);
    __bf16* zo = &zb[(size_t)row * CC];
#pragma unroll
    for (int i = 0; i < 12; i++) zo[l + i * 64] = f2bf(v[i] * s);
}

// ---------- K3: k/v projections (unchanged; Wk/Wv row-major) ----------
__global__ __launch_bounds__(256) void k_kv(const __bf16* __restrict__ zb,
        const __bf16* __restrict__ Wk, const float* __restrict__ bk,
        const __bf16* __restrict__ Wv, const float* __restrict__ bv,
        __bf16* __restrict__ kout, __bf16* __restrict__ vtout) {
    int ct = blockIdx.x, b = blockIdx.y, which = blockIdx.z;
    const __bf16* W = which ? Wv : Wk;
    const float* bias = which ? bv : bk;
    int t = threadIdx.x, w = t >> 6, l = t & 63, quad = l >> 4, l16 = l & 15;
    f4v acc[4][2];
#pragma unroll
    for (int i = 0; i < 4; i++) for (int j = 0; j < 2; j++) acc[i][j] = (f4v)0.0f;
    for (int k0 = 0; k0 < CC; k0 += 32) {
        bf8 afr[4], bfr[2];
#pragma unroll
        for (int sr = 0; sr < 4; sr++)
            afr[sr] = *(const bf8*)&zb[((size_t)(b * MM + sr * 16 + l16)) * CC + k0 + quad * 8];
#pragma unroll
        for (int sc = 0; sc < 2; sc++)
            bfr[sc] = *(const bf8*)&W[((size_t)(ct * 128 + w * 32 + sc * 16 + l16)) * CC + k0 + quad * 8];
#pragma unroll
        for (int sr = 0; sr < 4; sr++)
#pragma unroll
            for (int sc = 0; sc < 2; sc++)
                acc[sr][sc] = mfma16(afr[sr], bfr[sc], acc[sr][sc]);
    }
#pragma unroll
    for (int sr = 0; sr < 4; sr++)
#pragma unroll
        for (int sc = 0; sc < 2; sc++) {
            int col = ct * 128 + w * 32 + sc * 16 + l16;
            float bb = bias[col];
            int h = col >> 6, d = col & 63;
            if (which == 0) {
#pragma unroll
                for (int r = 0; r < 4; r++) {
                    int m = sr * 16 + quad * 4 + r;
                    kout[(((size_t)(b * HH + h)) * MM + m) * DD + d] = f2bf(acc[sr][sc][r] + bb);
                }
            } else {
                bf4 p;
#pragma unroll
                for (int r = 0; r < 4; r++) p[r] = f2bf(acc[sr][sc][r] + bb);
                *(bf4*)&vtout[(((size_t)(b * HH + h)) * DD + d) * MM + sr * 16 + quad * 4] = p;
            }
        }
}

// ======== zero-LDS 128x256 GEMM, 8 waves (2 row x 4 col), all frag-linear operands ========
// Per wave per K-step: 4 A-loads + 4 B-loads (coalesced 1KB each, L1/L2-hot) + 16 MFMA.
// No barriers, no waitcnt, no staging: 4 waves/SIMD TLP hides latency.

// ---------- K4: q = xb @ Wq^T + bq -> q FRAG-LINEAR [nt][h][kc][lane][8] ----------
__global__ __launch_bounds__(512, 2) void k_qproj(const __bf16* __restrict__ xb,
        const __bf16* __restrict__ Wq, const float* __restrict__ bq,
        __bf16* __restrict__ qb) {
    // 768 blocks = 8 XCD x 96 (32 row-stripes x 3 jt per chunk): A-stripe L2-local.
    int orig = blockIdx.x;
    int lid = (orig & 7) * 96 + (orig >> 3);
    int jt = lid % 3;
    size_t arow0 = (size_t)(lid / 3) * 128;
    int gt0 = (int)(arow0 >> 4);

    __shared__ __align__(16) __bf16 eb[128 * 72];   // epilogue transpose buffer (18 KB)
    int t = threadIdx.x, w = t >> 6, l = t & 63, quad = l >> 4, l16 = l & 15;
    int wm = w >> 2, wn = w & 3;   // 2x4 wave grid, per-wave 64x64
    f4v acc[4][4];
#pragma unroll
    for (int i = 0; i < 4; i++) for (int j = 0; j < 4; j++) acc[i][j] = (f4v)0.0f;

    for (int kc = 0; kc < 24; kc++) {
        bf8 afr[4], bfr[4];
#pragma unroll
        for (int sr = 0; sr < 4; sr++)
            afr[sr] = *(const bf8*)&xb[((size_t)((gt0 + wm * 4 + sr) * 24 + kc)) * 512 + l * 8];
#pragma unroll
        for (int sc = 0; sc < 4; sc++)
            bfr[sc] = *(const bf8*)&Wq[((size_t)((jt * 16 + wn * 4 + sc) * 24 + kc)) * 512 + l * 8];
#pragma unroll
        for (int sr = 0; sr < 4; sr++)
#pragma unroll
            for (int sc = 0; sc < 4; sc++)
                acc[sr][sc] = mfma16(afr[sr], bfr[sc], acc[sr][sc]);
    }

    // epilogue: 4 phases; phase p: the 2 waves with wn==p dump 128x64 (pad 72),
    // then all 512 threads store frag-linear q (head h = jt*4+p) with 1KB lines.
    for (int p = 0; p < 4; ++p) {
        if (wn == p) {
#pragma unroll
            for (int sc = 0; sc < 4; sc++) {
                int col = jt * 256 + p * 64 + sc * 16 + l16;
                float bb = bq[col];
#pragma unroll
                for (int sr = 0; sr < 4; sr++)
#pragma unroll
                    for (int r = 0; r < 4; r++)
                        eb[(wm * 64 + sr * 16 + quad * 4 + r) * 72 + sc * 16 + l16] = f2bf(acc[sr][sc][r] + bb);
            }
        }
        __syncthreads();
        int h = jt * 4 + p;
#pragma unroll
        for (int i = 0; i < 2; i++) {
            int idx = t + 512 * i, nt = idx >> 7, kcs = (idx >> 6) & 1, lane = idx & 63;
            bf8 v = *(const bf8*)&eb[(nt * 16 + (lane & 15)) * 72 + kcs * 32 + (lane >> 4) * 8];
            *(bf8*)&qb[((size_t)(((gt0 + nt) * 12 + h) * 2 + kcs)) * 512 + lane * 8] = v;
        }
        __syncthreads();
    }
}

// ---------- K5: attention (q frag-linear in, o frag-linear out; K/V paths unchanged) ----------
#define QS 72
__global__ __launch_bounds__(256) void k_attn(const __bf16* __restrict__ qb,
        const __bf16* __restrict__ kb, const __bf16* __restrict__ vt,
        __bf16* __restrict__ ob) {
    int n0 = blockIdx.x * 128, h = blockIdx.y, b = blockIdx.z;
    __shared__ __align__(16) __bf16 ps[128 * QS];
    int t = threadIdx.x, w = t >> 6, l = t & 63, quad = l >> 4, l16 = l & 15;
    size_t bh = (size_t)(b * HH + h);
    int nt0 = b * 64 + (n0 >> 4);

    f4v sacc[2][4];
#pragma unroll
    for (int i = 0; i < 2; i++) for (int j = 0; j < 4; j++) sacc[i][j] = (f4v)0.0f;
#pragma unroll
    for (int kc = 0; kc < 2; kc++) {
        bf8 afr[2], bfr[4];
#pragma unroll
        for (int sr = 0; sr < 2; sr++)
            afr[sr] = *(const bf8*)&qb[((size_t)(((nt0 + w * 2 + sr) * 12 + h) * 2 + kc)) * 512 + l * 8];
#pragma unroll
        for (int sc = 0; sc < 4; sc++)
            bfr[sc] = *(const bf8*)&kb[(bh * MM + sc * 16 + l16) * DD + kc * 32 + quad * 8];
#pragma unroll
        for (int sr = 0; sr < 2; sr++)
#pragma unroll
            for (int sc = 0; sc < 4; sc++)
                sacc[sr][sc] = mfma16(afr[sr], bfr[sc], sacc[sr][sc]);
    }
#pragma unroll
    for (int sr = 0; sr < 2; sr++) {
#pragma unroll
        for (int r = 0; r < 4; r++) {
            float mx = -1e30f;
#pragma unroll
            for (int sc = 0; sc < 4; sc++) mx = fmaxf(mx, sacc[sr][sc][r] * 0.125f);
#pragma unroll
            for (int off = 1; off < 16; off <<= 1) mx = fmaxf(mx, __shfl_xor(mx, off));
            float e[4]; float sum = 0.f;
#pragma unroll
            for (int sc = 0; sc < 4; sc++) { e[sc] = __expf(sacc[sr][sc][r] * 0.125f - mx); sum += e[sc]; }
#pragma unroll
            for (int off = 1; off < 16; off <<= 1) sum += __shfl_xor(sum, off);
            float inv = 1.0f / sum;
            int row = w * 32 + sr * 16 + quad * 4 + r;
#pragma unroll
            for (int sc = 0; sc < 4; sc++) ps[row * QS + sc * 16 + l16] = f2bf(e[sc] * inv);
        }
    }
    f4v oacc[2][4];
#pragma unroll
    for (int i = 0; i < 2; i++) for (int j = 0; j < 4; j++) oacc[i][j] = (f4v)0.0f;
#pragma unroll
    for (int kc = 0; kc < 2; kc++) {
        bf8 afr[2], bfr[4];
#pragma unroll
        for (int sr = 0; sr < 2; sr++)
            afr[sr] = *(const bf8*)&ps[(w * 32 + sr * 16 + l16) * QS + kc * 32 + quad * 8];
#pragma unroll
        for (int sc = 0; sc < 4; sc++)
            bfr[sc] = *(const bf8*)&vt[(bh * DD + sc * 16 + l16) * MM + kc * 32 + quad * 8];
#pragma unroll
        for (int sr = 0; sr < 2; sr++)
#pragma unroll
            for (int sc = 0; sc < 4; sc++)
                oacc[sr][sc] = mfma16(afr[sr], bfr[sc], oacc[sr][sc]);
    }
    // o-tile through ps, then FRAG-LINEAR stores (1KB lines)
#pragma unroll
    for (int sr = 0; sr < 2; sr++)
#pragma unroll
        for (int sc = 0; sc < 4; sc++) {
            int row = w * 32 + sr * 16;
#pragma unroll
            for (int r = 0; r < 4; r++)
                ps[(row + quad * 4 + r) * QS + sc * 16 + l16] = f2bf(oacc[sr][sc][r]);
        }
    __syncthreads();
#pragma unroll
    for (int i = 0; i < 4; i++) {
        int idx = t + 256 * i, nt = idx >> 7, kcs = (idx >> 6) & 1, lane = idx & 63;
        bf8 v = *(const bf8*)&ps[(nt * 16 + (lane & 15)) * QS + kcs * 32 + (lane >> 4) * 8];
        *(bf8*)&ob[((size_t)((nt0 + nt) * 24 + h * 2 + kcs)) * 512 + lane * 8] = v;
    }
}

// ---------- K6: out = o @ Wp^T + bp  (fp32 row-major out; zero-LDS main loop) ----------
__global__ __launch_bounds__(512, 2) void k_oproj(const __bf16* __restrict__ ob,
        const __bf16* __restrict__ Wp, const float* __restrict__ bp,
        float* __restrict__ out) {
    int orig = blockIdx.x;
    int lid = (orig & 7) * 96 + (orig >> 3);
    int jt = lid % 3;
    size_t arow0 = (size_t)(lid / 3) * 128;
    int gt0 = (int)(arow0 >> 4);

    __shared__ __align__(16) float ebf[128 * 68];   // fp32 epilogue (34 KB)
    int t = threadIdx.x, w = t >> 6, l = t & 63, quad = l >> 4, l16 = l & 15;
    int wm = w >> 2, wn = w & 3;
    f4v acc[4][4];
#pragma unroll
    for (int i = 0; i < 4; i++) for (int j = 0; j < 4; j++) acc[i][j] = (f4v)0.0f;

    for (int kc = 0; kc < 24; kc++) {
        bf8 afr[4], bfr[4];
#pragma unroll
        for (int sr = 0; sr < 4; sr++)
            afr[sr] = *(const bf8*)&ob[((size_t)((gt0 + wm * 4 + sr) * 24 + kc)) * 512 + l * 8];
#pragma unroll
        for (int sc = 0; sc < 4; sc++)
            bfr[sc] = *(const bf8*)&Wp[((size_t)((jt * 16 + wn * 4 + sc) * 24 + kc)) * 512 + l * 8];
#pragma unroll
        for (int sr = 0; sr < 4; sr++)
#pragma unroll
            for (int sc = 0; sc < 4; sc++)
                acc[sr][sc] = mfma16(afr[sr], bfr[sc], acc[sr][sc]);
    }

    for (int p = 0; p < 4; ++p) {
        if (wn == p) {
#pragma unroll
            for (int sc = 0; sc < 4; sc++) {
                int col = jt * 256 + p * 64 + sc * 16 + l16;
                float bb = bp[col];
#pragma unroll
                for (int sr = 0; sr < 4; sr++)
#pragma unroll
                    for (int r = 0; r < 4; r++)
                        ebf[(wm * 64 + sr * 16 + quad * 4 + r) * 68 + sc * 16 + l16] = acc[sr][sc][r] + bb;
            }
        }
        __syncthreads();
#pragma unroll
        for (int i = 0; i < 4; i++) {
            int idx = t + 512 * i, row = idx >> 4, c4 = idx & 15;
            *(float4*)&out[(arow0 + row) * CC + jt * 256 + p * 64 + c4 * 4] = *(const float4*)&ebf[row * 68 + c4 * 4];
        }
        __syncthreads();
    }
}

extern "C" void kernel_launch(void* const* d_in, const int* in_sizes, int n_in,
                              void* d_out, int out_size, void* d_ws, size_t ws_size,
                              hipStream_t stream) {
    (void)in_sizes; (void)n_in; (void)out_size; (void)ws_size;
    const float* x  = (const float*)d_in[0];
    const float* Wc = (const float*)d_in[1];
    const float* bc = (const float*)d_in[2];
    const float* Wq = (const float*)d_in[3];
    const float* bq = (const float*)d_in[4];
    const float* Wk = (const float*)d_in[5];
    const float* bk = (const float*)d_in[6];
    const float* Wv = (const float*)d_in[7];
    const float* bv = (const float*)d_in[8];
    const float* Wp = (const float*)d_in[9];
    const float* bp = (const float*)d_in[10];
    float* out = (float*)d_out;

    char* ws = (char*)d_ws;
    size_t off = 0;
    auto alloc = [&](size_t bytes) { void* p = ws + off; off = (off + bytes + 255) & ~(size_t)255; return p; };
    __bf16* wc_b = (__bf16*)alloc((size_t)MM * CC * 2);
    __bf16* wq_b = (__bf16*)alloc((size_t)CC * CC * 2);
    __bf16* wk_b = (__bf16*)alloc((size_t)CC * CC * 2);
    __bf16* wv_b = (__bf16*)alloc((size_t)CC * CC * 2);
    __bf16* wp_b = (__bf16*)alloc((size_t)CC * CC * 2);
    __bf16* xb   = (__bf16*)alloc((size_t)BB * NN * CC * 2);
    __bf16* xt_o = (__bf16*)alloc((size_t)BB * NN * CC * 2);  // xt, reused as o (frag)
    __bf16* q_b  = (__bf16*)alloc((size_t)BB * NN * CC * 2);
    __bf16* c_bmn= (__bf16*)alloc((size_t)BB * MM * NN * 2);
    float*  z_f  = (float*) alloc((size_t)BB * MM * CC * 4);
    __bf16* z_b  = (__bf16*)alloc((size_t)BB * MM * CC * 2);
    __bf16* k_b  = (__bf16*)alloc((size_t)BB * HH * MM * DD * 2);
    __bf16* v_t  = (__bf16*)alloc((size_t)BB * HH * MM * DD * 2);

    k_cvtW<<<dim3((CC * CC / 4 + 255) / 256, 5), 256, 0, stream>>>(
        Wc, Wq, Wk, Wv, Wp, wc_b, wq_b, wk_b, wv_b, wp_b);

    k_cvtx<<<dim3(CC / 64, NN / 64, BB), 256, 0, stream>>>(x, xb, xt_o);
    k_cluster<<<dim3(NN / 128, BB), 256, 0, stream>>>(xb, wc_b, bc, c_bmn);
    k_z<<<dim3(CC / 64, BB), 256, 0, stream>>>(c_bmn, xt_o, z_f);
    k_znorm<<<(BB * MM) / 4, 256, 0, stream>>>(z_f, z_b);
    k_kv<<<dim3(CC / 128, BB, 2), 256, 0, stream>>>(z_b, wk_b, bk, wv_b, bv, k_b, v_t);
    k_qproj<<<dim3((BB * NN / 128) * 3), 512, 0, stream>>>(xb, wq_b, bq, q_b);
    k_attn<<<dim3(NN / 128, HH, BB), 256, 0, stream>>>(q_b, k_b, v_t, xt_o /* o reuses xt */);
    k_oproj<<<dim3((BB * NN / 128) * 3), 512, 0, stream>>>(xt_o, wp_b, bp, out);
}

// Round 8
// 282.044 us; speedup vs baseline: 1.1165x; 1.0470x over previous
//
#include <hip/hip_runtime.h>
#include <hip/hip_bf16.h>
#include <cstdint>

// ---- problem constants ----
#define BB 32
#define NN 1024
#define CC 768
#define MM 64
#define HH 12
#define DD 64

typedef float f4v __attribute__((ext_vector_type(4)));
typedef __bf16 bf8 __attribute__((ext_vector_type(8)));
typedef __bf16 bf4 __attribute__((ext_vector_type(4)));

__device__ __forceinline__ f4v mfma16(bf8 a, bf8 b, f4v c) {
    return __builtin_amdgcn_mfma_f32_16x16x32_bf16(a, b, c, 0, 0, 0);
}
__device__ __forceinline__ __bf16 f2bf(float f) { return (__bf16)f; }

__device__ __forceinline__ void gl2lds16(const void* g, void* lds) {
    __builtin_amdgcn_global_load_lds((const __attribute__((address_space(1))) void*)g,
                                     (__attribute__((address_space(3))) void*)lds, 16, 0, 0);
}

// ================= fragment-linear layout (lane-order) =================
// frag[tile16][kc32][lane64][8]: element (row, k) at
//   tile = row>>4, kc = k>>5, LANE = ((k>>3)&3)*16 + (row&15), e = k&7
// A wave's fragment load = base + l*8 -> one coalesced 1KB line; lane l gets
// exactly its MFMA fragment element. Staging such a block into LDS keeps it
// lane-ordered -> ds_read at base+l*8 is stride-1 across the wave: conflict-free.

// ---------- all weights fp32 -> bf16; Wc/Wq/Wp FRAG-LINEAR, Wk/Wv row-major ----------
__global__ __launch_bounds__(256) void k_cvtW(
        const float* __restrict__ Wc, const float* __restrict__ Wq,
        const float* __restrict__ Wk, const float* __restrict__ Wv,
        const float* __restrict__ Wp,
        __bf16* __restrict__ wc, __bf16* __restrict__ wq,
        __bf16* __restrict__ wk, __bf16* __restrict__ wv,
        __bf16* __restrict__ wp) {
    const float* in; __bf16* out; int n4; int frag;
    switch (blockIdx.y) {
        case 0: in = Wc; out = wc; n4 = MM * CC / 4; frag = 1; break;
        case 1: in = Wq; out = wq; n4 = CC * CC / 4; frag = 1; break;
        case 2: in = Wk; out = wk; n4 = CC * CC / 4; frag = 0; break;
        case 3: in = Wv; out = wv; n4 = CC * CC / 4; frag = 0; break;
        default: in = Wp; out = wp; n4 = CC * CC / 4; frag = 1; break;
    }
    int i = blockIdx.x * 256 + threadIdx.x;
    if (i < n4) {
        float4 v = *(const float4*)&in[i * 4];
        bf4 o; o[0] = f2bf(v.x); o[1] = f2bf(v.y); o[2] = f2bf(v.z); o[3] = f2bf(v.w);
        if (frag) {
            int lin = i * 4, m = lin / CC, c = lin % CC;
            size_t off = ((size_t)((m >> 4) * 24 + (c >> 5))) * 512
                       + ((((c >> 3) & 3) * 16) + (m & 15)) * 8 + (c & 7);
            *(bf4*)&out[off] = o;
        } else {
            *(bf4*)&out[i * 4] = o;
        }
    }
}

// ---------- K0: x -> xb FRAG-LINEAR bf16  AND  xt (b,c,n) row-major via padded LDS transpose ----------
__global__ __launch_bounds__(256) void k_cvtx(const float* __restrict__ x,
        __bf16* __restrict__ xb, __bf16* __restrict__ xt) {
    int c0 = blockIdx.x * 64, n0 = blockIdx.y * 64, b = blockIdx.z;
    __shared__ __align__(16) __bf16 tileT[64 * 66];
    int t = threadIdx.x;
#pragma unroll
    for (int i = 0; i < 4; i++) {
        int idx = t + 256 * i, r = idx >> 4, cq = idx & 15;
        float4 v = *(const float4*)&x[((size_t)(b * NN + n0 + r)) * CC + c0 + cq * 4];
        float vv[4] = {v.x, v.y, v.z, v.w};
        bf4 o;
#pragma unroll
        for (int j = 0; j < 4; j++) {
            __bf16 bv = f2bf(vv[j]);
            o[j] = bv;
            tileT[(cq * 4 + j) * 66 + r] = bv;
        }
        int nt = b * 64 + (n0 >> 4) + (r >> 4);
        int kc = (c0 >> 5) + (cq >> 3);
        int quad = (cq >> 1) & 3;
        int e0 = (cq & 1) * 4;
        *(bf4*)&xb[((size_t)(nt * 24 + kc)) * 512 + (quad * 16 + (r & 15)) * 8 + e0] = o;
    }
    __syncthreads();
#pragma unroll
    for (int i = 0; i < 2; i++) {
        int idx = t + 256 * i, c = idx >> 3, ch = idx & 7;
        bf8 v2 = *(const bf8*)&tileT[c * 66 + ch * 8];
        *(bf8*)&xt[((size_t)(b * CC + c0 + c)) * NN + n0 + ch * 8] = v2;
    }
}

// ---------- K1: c_bmn = sigmoid(x@Wc^T + bc)/N  (frag-linear operand loads) ----------
__global__ __launch_bounds__(256) void k_cluster(const __bf16* __restrict__ xb,
        const __bf16* __restrict__ Wc, const float* __restrict__ bc,
        __bf16* __restrict__ cbmn) {
    int n0 = blockIdx.x * 128, b = blockIdx.y;
    int t = threadIdx.x, w = t >> 6, l = t & 63, quad = (l >> 4), l16 = l & 15;
    int nt0 = b * 64 + (n0 >> 4);
    f4v acc[2][4];
#pragma unroll
    for (int i = 0; i < 2; i++) for (int j = 0; j < 4; j++) acc[i][j] = (f4v)0.0f;
    for (int kc = 0; kc < 24; kc++) {
        bf8 afr[2], bfr[4];
#pragma unroll
        for (int sr = 0; sr < 2; sr++)
            afr[sr] = *(const bf8*)&xb[((size_t)((nt0 + w * 2 + sr) * 24 + kc)) * 512 + l * 8];
#pragma unroll
        for (int sc = 0; sc < 4; sc++)
            bfr[sc] = *(const bf8*)&Wc[((size_t)(sc * 24 + kc)) * 512 + l * 8];
#pragma unroll
        for (int sr = 0; sr < 2; sr++)
#pragma unroll
            for (int sc = 0; sc < 4; sc++)
                acc[sr][sc] = mfma16(afr[sr], bfr[sc], acc[sr][sc]);
    }
#pragma unroll
    for (int sr = 0; sr < 2; sr++)
#pragma unroll
        for (int sc = 0; sc < 4; sc++) {
            int m = sc * 16 + l16;
            float bias = bc[m];
            bf4 p;
#pragma unroll
            for (int r = 0; r < 4; r++) {
                float val = acc[sr][sc][r] + bias;
                val = 1.0f / (1.0f + __expf(-val));
                p[r] = f2bf(val * (1.0f / 1024.0f));
            }
            *(bf4*)&cbmn[((size_t)(b * MM + m)) * NN + n0 + w * 32 + sr * 16 + quad * 4] = p;
        }
}

// ---------- K2: z[b,m,c] = sum_n c_bmn * xt   (unchanged) ----------
__global__ __launch_bounds__(256) void k_z(const __bf16* __restrict__ cbmn,
        const __bf16* __restrict__ xt, float* __restrict__ z) {
    int c0 = blockIdx.x * 64, b = blockIdx.y;
    int t = threadIdx.x, w = t >> 6, l = t & 63, quad = l >> 4, l16 = l & 15;
    f4v acc[4];
#pragma unroll
    for (int j = 0; j < 4; j++) acc[j] = (f4v)0.0f;
    for (int n0 = 0; n0 < NN; n0 += 32) {
        bf8 afr = *(const bf8*)&cbmn[((size_t)(b * MM + w * 16 + l16)) * NN + n0 + quad * 8];
#pragma unroll
        for (int sc = 0; sc < 4; sc++) {
            bf8 bfr = *(const bf8*)&xt[((size_t)(b * CC + c0 + sc * 16 + l16)) * NN + n0 + quad * 8];
            acc[sc] = mfma16(afr, bfr, acc[sc]);
        }
    }
#pragma unroll
    for (int sc = 0; sc < 4; sc++) {
        int cc = c0 + sc * 16 + l16;
#pragma unroll
        for (int r = 0; r < 4; r++) {
            int m = w * 16 + quad * 4 + r;
            z[((size_t)(b * MM + m)) * CC + cc] = acc[sc][r];
        }
    }
}

// ---------- K2b: L2-normalize rows of z, write bf16 (unchanged) ----------
__global__ __launch_bounds__(256) void k_znorm(const float* __restrict__ z, __bf16* __restrict__ zb) {
    int w = threadIdx.x >> 6, l = threadIdx.x & 63;
    int row = blockIdx.x * 4 + w;
    const float* zr = &z[(size_t)row * CC];
    float v[12]; float ss = 0.f;
#pragma unroll
    for (int i = 0; i < 12; i++) { v[i] = zr[l + i * 64]; ss += v[i] * v[i]; }
#pragma unroll
    for (int off = 32; off; off >>= 1) ss += __shfl_xor(ss, off);
    float s = 1.0f / fmaxf(sqrtf(ss), 1e-12f);
    __bf16* zo = &zb[(size_t)row * CC];
#pragma unroll
    for (int i = 0; i < 12; i++) zo[l + i * 64] = f2bf(v[i] * s);
}

// ---------- K3: k/v projections (unchanged; Wk/Wv row-major) ----------
__global__ __launch_bounds__(256) void k_kv(const __bf16* __restrict__ zb,
        const __bf16* __restrict__ Wk, const float* __restrict__ bk,
        const __bf16* __restrict__ Wv, const float* __restrict__ bv,
        __bf16* __restrict__ kout, __bf16* __restrict__ vtout) {
    int ct = blockIdx.x, b = blockIdx.y, which = blockIdx.z;
    const __bf16* W = which ? Wv : Wk;
    const float* bias = which ? bv : bk;
    int t = threadIdx.x, w = t >> 6, l = t & 63, quad = l >> 4, l16 = l & 15;
    f4v acc[4][2];
#pragma unroll
    for (int i = 0; i < 4; i++) for (int j = 0; j < 2; j++) acc[i][j] = (f4v)0.0f;
    for (int k0 = 0; k0 < CC; k0 += 32) {
        bf8 afr[4], bfr[2];
#pragma unroll
        for (int sr = 0; sr < 4; sr++)
            afr[sr] = *(const bf8*)&zb[((size_t)(b * MM + sr * 16 + l16)) * CC + k0 + quad * 8];
#pragma unroll
        for (int sc = 0; sc < 2; sc++)
            bfr[sc] = *(const bf8*)&W[((size_t)(ct * 128 + w * 32 + sc * 16 + l16)) * CC + k0 + quad * 8];
#pragma unroll
        for (int sr = 0; sr < 4; sr++)
#pragma unroll
            for (int sc = 0; sc < 2; sc++)
                acc[sr][sc] = mfma16(afr[sr], bfr[sc], acc[sr][sc]);
    }
#pragma unroll
    for (int sr = 0; sr < 4; sr++)
#pragma unroll
        for (int sc = 0; sc < 2; sc++) {
            int col = ct * 128 + w * 32 + sc * 16 + l16;
            float bb = bias[col];
            int h = col >> 6, d = col & 63;
            if (which == 0) {
#pragma unroll
                for (int r = 0; r < 4; r++) {
                    int m = sr * 16 + quad * 4 + r;
                    kout[(((size_t)(b * HH + h)) * MM + m) * DD + d] = f2bf(acc[sr][sc][r] + bb);
                }
            } else {
                bf4 p;
#pragma unroll
                for (int r = 0; r < 4; r++) p[r] = f2bf(acc[sr][sc][r] + bb);
                *(bf4*)&vtout[(((size_t)(b * HH + h)) * DD + d) * MM + sr * 16 + quad * 4] = p;
            }
        }
}

// ======== HYBRID 128x256 GEMM: A staged via LDS (frag-linear blocks, depth-3),
//          B direct frag-linear global. 4 waves, per-wave 128x64 (8x4 frags).
// A stage = 8 x 1KB lane-ordered blocks per K-chunk (8KB/buf); gl2lds dest is
// linear lane-order -> ds_read at base+l*16B is stride-1: conflict-free, no swizzle.
// Per iter: 4 B-loads (coalesced 1KB, L2-hot) + 8 ds_reads + 32 MFMA.
// depth-3: stage kt+2 each iter; vmcnt(2) keeps it in flight across the barrier.
#define STAGE_AF(Asrc, buf, kcs)                                                      \
    do {                                                                              \
        __bf16* _d = (buf);                                                           \
        gl2lds16(&(Asrc)[((size_t)((gt0 + w) * 24 + (kcs))) * 512 + l * 8], &_d[w * 512]); \
        gl2lds16(&(Asrc)[((size_t)((gt0 + w + 4) * 24 + (kcs))) * 512 + l * 8], &_d[(w + 4) * 512]); \
    } while (0)

#define GEMM_KLOOP_H(Asrc, Bsrc)                                                      \
    STAGE_AF(Asrc, As3, 0);                                                           \
    STAGE_AF(Asrc, As3 + 4096, 1);                                                    \
    asm volatile("s_waitcnt vmcnt(2)" ::: "memory");                                  \
    __builtin_amdgcn_s_barrier();                                                     \
    for (int kt = 0; kt < 24; ++kt) {                                                 \
        const __bf16* As = As3 + (kt % 3) * 4096;                                     \
        bf8 bfr[4], afr[8];                                                           \
        _Pragma("unroll")                                                             \
        for (int sc = 0; sc < 4; sc++)                                                \
            bfr[sc] = *(const bf8*)&(Bsrc)[((size_t)((jt * 16 + w * 4 + sc) * 24 + kt)) * 512 + l * 8]; \
        _Pragma("unroll")                                                             \
        for (int sr = 0; sr < 8; sr++)                                                \
            afr[sr] = *(const bf8*)&As[sr * 512 + l * 8];                             \
        __builtin_amdgcn_sched_barrier(0);                                            \
        if (kt < 22) STAGE_AF(Asrc, As3 + ((kt + 2) % 3) * 4096, kt + 2);             \
        __builtin_amdgcn_s_setprio(1);                                                \
        _Pragma("unroll")                                                             \
        for (int sr = 0; sr < 8; sr++)                                                \
            _Pragma("unroll")                                                         \
            for (int sc = 0; sc < 4; sc++)                                            \
                acc[sr][sc] = mfma16(afr[sr], bfr[sc], acc[sr][sc]);                  \
        __builtin_amdgcn_s_setprio(0);                                                \
        asm volatile("s_waitcnt vmcnt(2)" ::: "memory");                              \
        __builtin_amdgcn_s_barrier();                                                 \
    }

// ---------- K4: q = xb @ Wq^T + bq -> q FRAG-LINEAR [nt][h][kcs][lane][8] ----------
__global__ __launch_bounds__(256, 2) void k_qproj(const __bf16* __restrict__ xb,
        const __bf16* __restrict__ Wq, const float* __restrict__ bq,
        __bf16* __restrict__ qb) {
    // 768 blocks = 8 XCD x 96 (32 row-stripes x 3 jt per chunk): A-stripe L2-local.
    int orig = blockIdx.x;
    int lid = (orig & 7) * 96 + (orig >> 3);
    int jt = lid % 3;
    int gt0 = (lid / 3) * 8;   // 8 row-tiles = 128 rows

    __shared__ __align__(16) __bf16 As3[3 * 4096];  // 24 KB A triple-buffer
    __shared__ __align__(16) __bf16 eb[128 * 72];   // 18 KB epilogue
    int t = threadIdx.x, w = t >> 6, l = t & 63, quad = l >> 4, l16 = l & 15;
    f4v acc[8][4];
#pragma unroll
    for (int i = 0; i < 8; i++) for (int j = 0; j < 4; j++) acc[i][j] = (f4v)0.0f;

    GEMM_KLOOP_H(xb, Wq);

    // epilogue: 4 phases; phase p: wave p dumps its 128x64 (pad 72); all threads
    // then store frag-linear q for head h = jt*4+p with contiguous 1KB lines.
    for (int p = 0; p < 4; ++p) {
        if (w == p) {
#pragma unroll
            for (int sc = 0; sc < 4; sc++) {
                int col = jt * 256 + p * 64 + sc * 16 + l16;
                float bb = bq[col];
#pragma unroll
                for (int sr = 0; sr < 8; sr++)
#pragma unroll
                    for (int r = 0; r < 4; r++)
                        eb[(sr * 16 + quad * 4 + r) * 72 + sc * 16 + l16] = f2bf(acc[sr][sc][r] + bb);
            }
        }
        __syncthreads();
        int h = jt * 4 + p;
#pragma unroll
        for (int i = 0; i < 4; i++) {
            int idx = t + 256 * i, nt = idx >> 7, kcs = (idx >> 6) & 1, lane = idx & 63;
            bf8 v = *(const bf8*)&eb[(nt * 16 + (lane & 15)) * 72 + kcs * 32 + (lane >> 4) * 8];
            *(bf8*)&qb[((size_t)(((gt0 + nt) * 12 + h) * 2 + kcs)) * 512 + lane * 8] = v;
        }
        __syncthreads();
    }
}

// ---------- K5: attention (q frag-linear in, o frag-linear out; K/V unchanged) ----------
#define QS 72
__global__ __launch_bounds__(256) void k_attn(const __bf16* __restrict__ qb,
        const __bf16* __restrict__ kb, const __bf16* __restrict__ vt,
        __bf16* __restrict__ ob) {
    int n0 = blockIdx.x * 128, h = blockIdx.y, b = blockIdx.z;
    __shared__ __align__(16) __bf16 ps[128 * QS];
    int t = threadIdx.x, w = t >> 6, l = t & 63, quad = l >> 4, l16 = l & 15;
    size_t bh = (size_t)(b * HH + h);
    int nt0 = b * 64 + (n0 >> 4);

    f4v sacc[2][4];
#pragma unroll
    for (int i = 0; i < 2; i++) for (int j = 0; j < 4; j++) sacc[i][j] = (f4v)0.0f;
#pragma unroll
    for (int kc = 0; kc < 2; kc++) {
        bf8 afr[2], bfr[4];
#pragma unroll
        for (int sr = 0; sr < 2; sr++)
            afr[sr] = *(const bf8*)&qb[((size_t)(((nt0 + w * 2 + sr) * 12 + h) * 2 + kc)) * 512 + l * 8];
#pragma unroll
        for (int sc = 0; sc < 4; sc++)
            bfr[sc] = *(const bf8*)&kb[(bh * MM + sc * 16 + l16) * DD + kc * 32 + quad * 8];
#pragma unroll
        for (int sr = 0; sr < 2; sr++)
#pragma unroll
            for (int sc = 0; sc < 4; sc++)
                sacc[sr][sc] = mfma16(afr[sr], bfr[sc], sacc[sr][sc]);
    }
#pragma unroll
    for (int sr = 0; sr < 2; sr++) {
#pragma unroll
        for (int r = 0; r < 4; r++) {
            float mx = -1e30f;
#pragma unroll
            for (int sc = 0; sc < 4; sc++) mx = fmaxf(mx, sacc[sr][sc][r] * 0.125f);
#pragma unroll
            for (int off = 1; off < 16; off <<= 1) mx = fmaxf(mx, __shfl_xor(mx, off));
            float e[4]; float sum = 0.f;
#pragma unroll
            for (int sc = 0; sc < 4; sc++) { e[sc] = __expf(sacc[sr][sc][r] * 0.125f - mx); sum += e[sc]; }
#pragma unroll
            for (int off = 1; off < 16; off <<= 1) sum += __shfl_xor(sum, off);
            float inv = 1.0f / sum;
            int row = w * 32 + sr * 16 + quad * 4 + r;
#pragma unroll
            for (int sc = 0; sc < 4; sc++) ps[row * QS + sc * 16 + l16] = f2bf(e[sc] * inv);
        }
    }
    f4v oacc[2][4];
#pragma unroll
    for (int i = 0; i < 2; i++) for (int j = 0; j < 4; j++) oacc[i][j] = (f4v)0.0f;
#pragma unroll
    for (int kc = 0; kc < 2; kc++) {
        bf8 afr[2], bfr[4];
#pragma unroll
        for (int sr = 0; sr < 2; sr++)
            afr[sr] = *(const bf8*)&ps[(w * 32 + sr * 16 + l16) * QS + kc * 32 + quad * 8];
#pragma unroll
        for (int sc = 0; sc < 4; sc++)
            bfr[sc] = *(const bf8*)&vt[(bh * DD + sc * 16 + l16) * MM + kc * 32 + quad * 8];
#pragma unroll
        for (int sr = 0; sr < 2; sr++)
#pragma unroll
            for (int sc = 0; sc < 4; sc++)
                oacc[sr][sc] = mfma16(afr[sr], bfr[sc], oacc[sr][sc]);
    }
#pragma unroll
    for (int sr = 0; sr < 2; sr++)
#pragma unroll
        for (int sc = 0; sc < 4; sc++) {
            int row = w * 32 + sr * 16;
#pragma unroll
            for (int r = 0; r < 4; r++)
                ps[(row + quad * 4 + r) * QS + sc * 16 + l16] = f2bf(oacc[sr][sc][r]);
        }
    __syncthreads();
#pragma unroll
    for (int i = 0; i < 4; i++) {
        int idx = t + 256 * i, nt = idx >> 7, kcs = (idx >> 6) & 1, lane = idx & 63;
        bf8 v = *(const bf8*)&ps[(nt * 16 + (lane & 15)) * QS + kcs * 32 + (lane >> 4) * 8];
        *(bf8*)&ob[((size_t)((nt0 + nt) * 24 + h * 2 + kcs)) * 512 + lane * 8] = v;
    }
}

// ---------- K6: out = o @ Wp^T + bp  (o frag-linear in, fp32 row-major out) ----------
__global__ __launch_bounds__(256, 2) void k_oproj(const __bf16* __restrict__ ob,
        const __bf16* __restrict__ Wp, const float* __restrict__ bp,
        float* __restrict__ out) {
    int orig = blockIdx.x;
    int lid = (orig & 7) * 96 + (orig >> 3);
    int jt = lid % 3;
    int gt0 = (lid / 3) * 8;
    size_t arow0 = (size_t)(lid / 3) * 128;

    __shared__ __align__(16) __bf16 As3[3 * 4096];  // 24 KB
    __shared__ __align__(16) float ebf[128 * 68];   // 34 KB fp32 epilogue
    int t = threadIdx.x, w = t >> 6, l = t & 63, quad = l >> 4, l16 = l & 15;
    f4v acc[8][4];
#pragma unroll
    for (int i = 0; i < 8; i++) for (int j = 0; j < 4; j++) acc[i][j] = (f4v)0.0f;

    GEMM_KLOOP_H(ob, Wp);

    for (int p = 0; p < 4; ++p) {
        if (w == p) {
#pragma unroll
            for (int sc = 0; sc < 4; sc++) {
                int col = jt * 256 + p * 64 + sc * 16 + l16;
                float bb = bp[col];
#pragma unroll
                for (int sr = 0; sr < 8; sr++)
#pragma unroll
                    for (int r = 0; r < 4; r++)
                        ebf[(sr * 16 + quad * 4 + r) * 68 + sc * 16 + l16] = acc[sr][sc][r] + bb;
            }
        }
        __syncthreads();
#pragma unroll
        for (int i = 0; i < 8; i++) {
            int idx = t + 256 * i, row = idx >> 4, c4 = idx & 15;
            *(float4*)&out[(arow0 + row) * CC + jt * 256 + p * 64 + c4 * 4] = *(const float4*)&ebf[row * 68 + c4 * 4];
        }
        __syncthreads();
    }
}

extern "C" void kernel_launch(void* const* d_in, const int* in_sizes, int n_in,
                              void* d_out, int out_size, void* d_ws, size_t ws_size,
                              hipStream_t stream) {
    (void)in_sizes; (void)n_in; (void)out_size; (void)ws_size;
    const float* x  = (const float*)d_in[0];
    const float* Wc = (const float*)d_in[1];
    const float* bc = (const float*)d_in[2];
    const float* Wq = (const float*)d_in[3];
    const float* bq = (const float*)d_in[4];
    const float* Wk = (const float*)d_in[5];
    const float* bk = (const float*)d_in[6];
    const float* Wv = (const float*)d_in[7];
    const float* bv = (const float*)d_in[8];
    const float* Wp = (const float*)d_in[9];
    const float* bp = (const float*)d_in[10];
    float* out = (float*)d_out;

    char* ws = (char*)d_ws;
    size_t off = 0;
    auto alloc = [&](size_t bytes) { void* p = ws + off; off = (off + bytes + 255) & ~(size_t)255; return p; };
    __bf16* wc_b = (__bf16*)alloc((size_t)MM * CC * 2);
    __bf16* wq_b = (__bf16*)alloc((size_t)CC * CC * 2);
    __bf16* wk_b = (__bf16*)alloc((size_t)CC * CC * 2);
    __bf16* wv_b = (__bf16*)alloc((size_t)CC * CC * 2);
    __bf16* wp_b = (__bf16*)alloc((size_t)CC * CC * 2);
    __bf16* xb   = (__bf16*)alloc((size_t)BB * NN * CC * 2);
    __bf16* xt_o = (__bf16*)alloc((size_t)BB * NN * CC * 2);  // xt, reused as o (frag)
    __bf16* q_b  = (__bf16*)alloc((size_t)BB * NN * CC * 2);
    __bf16* c_bmn= (__bf16*)alloc((size_t)BB * MM * NN * 2);
    float*  z_f  = (float*) alloc((size_t)BB * MM * CC * 4);
    __bf16* z_b  = (__bf16*)alloc((size_t)BB * MM * CC * 2);
    __bf16* k_b  = (__bf16*)alloc((size_t)BB * HH * MM * DD * 2);
    __bf16* v_t  = (__bf16*)alloc((size_t)BB * HH * MM * DD * 2);

    k_cvtW<<<dim3((CC * CC / 4 + 255) / 256, 5), 256, 0, stream>>>(
        Wc, Wq, Wk, Wv, Wp, wc_b, wq_b, wk_b, wv_b, wp_b);

    k_cvtx<<<dim3(CC / 64, NN / 64, BB), 256, 0, stream>>>(x, xb, xt_o);
    k_cluster<<<dim3(NN / 128, BB), 256, 0, stream>>>(xb, wc_b, bc, c_bmn);
    k_z<<<dim3(CC / 64, BB), 256, 0, stream>>>(c_bmn, xt_o, z_f);
    k_znorm<<<(BB * MM) / 4, 256, 0, stream>>>(z_f, z_b);
    k_kv<<<dim3(CC / 128, BB, 2), 256, 0, stream>>>(z_b, wk_b, bk, wv_b, bv, k_b, v_t);
    k_qproj<<<dim3((BB * NN / 128) * 3), 256, 0, stream>>>(xb, wq_b, bq, q_b);
    k_attn<<<dim3(NN / 128, HH, BB), 256, 0, stream>>>(q_b, k_b, v_t, xt_o /* o reuses xt */);
    k_oproj<<<dim3((BB * NN / 128) * 3), 256, 0, stream>>>(xt_o, wp_b, bp, out);
}

// Round 9
// 265.883 us; speedup vs baseline: 1.1843x; 1.0608x over previous
//
#include <hip/hip_runtime.h>
#include <hip/hip_bf16.h>
#include <cstdint>

// ---- problem constants ----
#define BB 32
#define NN 1024
#define CC 768
#define MM 64
#define HH 12
#define DD 64

typedef float f4v __attribute__((ext_vector_type(4)));
typedef __bf16 bf8 __attribute__((ext_vector_type(8)));
typedef __bf16 bf4 __attribute__((ext_vector_type(4)));

__device__ __forceinline__ f4v mfma16(bf8 a, bf8 b, f4v c) {
    return __builtin_amdgcn_mfma_f32_16x16x32_bf16(a, b, c, 0, 0, 0);
}
__device__ __forceinline__ __bf16 f2bf(float f) { return (__bf16)f; }

__device__ __forceinline__ void gl2lds16(const void* g, void* lds) {
    __builtin_amdgcn_global_load_lds((const __attribute__((address_space(1))) void*)g,
                                     (__attribute__((address_space(3))) void*)lds, 16, 0, 0);
}

// ================= fragment-linear layout (lane-order) =================
// frag[tile16][kc32][lane64][8]: element (row, k) at
//   tile = row>>4, kc = k>>5, LANE = ((k>>3)&3)*16 + (row&15), e = k&7
// A wave's fragment load = base + l*8 -> one coalesced 1KB line; lane l gets
// exactly its MFMA fragment element. Staged blocks stay lane-ordered in LDS ->
// ds_read at base+l*16B is stride-1 across the wave: conflict-free, no swizzle.

// ---------- all weights fp32 -> bf16; Wc/Wq/Wp FRAG-LINEAR, Wk/Wv row-major ----------
__global__ __launch_bounds__(256) void k_cvtW(
        const float* __restrict__ Wc, const float* __restrict__ Wq,
        const float* __restrict__ Wk, const float* __restrict__ Wv,
        const float* __restrict__ Wp,
        __bf16* __restrict__ wc, __bf16* __restrict__ wq,
        __bf16* __restrict__ wk, __bf16* __restrict__ wv,
        __bf16* __restrict__ wp) {
    const float* in; __bf16* out; int n4; int frag;
    switch (blockIdx.y) {
        case 0: in = Wc; out = wc; n4 = MM * CC / 4; frag = 1; break;
        case 1: in = Wq; out = wq; n4 = CC * CC / 4; frag = 1; break;
        case 2: in = Wk; out = wk; n4 = CC * CC / 4; frag = 0; break;
        case 3: in = Wv; out = wv; n4 = CC * CC / 4; frag = 0; break;
        default: in = Wp; out = wp; n4 = CC * CC / 4; frag = 1; break;
    }
    int i = blockIdx.x * 256 + threadIdx.x;
    if (i < n4) {
        float4 v = *(const float4*)&in[i * 4];
        bf4 o; o[0] = f2bf(v.x); o[1] = f2bf(v.y); o[2] = f2bf(v.z); o[3] = f2bf(v.w);
        if (frag) {
            int lin = i * 4, m = lin / CC, c = lin % CC;
            size_t off = ((size_t)((m >> 4) * 24 + (c >> 5))) * 512
                       + ((((c >> 3) & 3) * 16) + (m & 15)) * 8 + (c & 7);
            *(bf4*)&out[off] = o;
        } else {
            *(bf4*)&out[i * 4] = o;
        }
    }
}

// ---------- K0: x -> xb FRAG-LINEAR bf16  AND  xt (b,c,n) row-major via padded LDS transpose ----------
__global__ __launch_bounds__(256) void k_cvtx(const float* __restrict__ x,
        __bf16* __restrict__ xb, __bf16* __restrict__ xt) {
    int c0 = blockIdx.x * 64, n0 = blockIdx.y * 64, b = blockIdx.z;
    __shared__ __align__(16) __bf16 tileT[64 * 66];
    int t = threadIdx.x;
#pragma unroll
    for (int i = 0; i < 4; i++) {
        int idx = t + 256 * i, r = idx >> 4, cq = idx & 15;
        float4 v = *(const float4*)&x[((size_t)(b * NN + n0 + r)) * CC + c0 + cq * 4];
        float vv[4] = {v.x, v.y, v.z, v.w};
        bf4 o;
#pragma unroll
        for (int j = 0; j < 4; j++) {
            __bf16 bv = f2bf(vv[j]);
            o[j] = bv;
            tileT[(cq * 4 + j) * 66 + r] = bv;
        }
        int nt = b * 64 + (n0 >> 4) + (r >> 4);
        int kc = (c0 >> 5) + (cq >> 3);
        int quad = (cq >> 1) & 3;
        int e0 = (cq & 1) * 4;
        *(bf4*)&xb[((size_t)(nt * 24 + kc)) * 512 + (quad * 16 + (r & 15)) * 8 + e0] = o;
    }
    __syncthreads();
#pragma unroll
    for (int i = 0; i < 2; i++) {
        int idx = t + 256 * i, c = idx >> 3, ch = idx & 7;
        bf8 v2 = *(const bf8*)&tileT[c * 66 + ch * 8];
        *(bf8*)&xt[((size_t)(b * CC + c0 + c)) * NN + n0 + ch * 8] = v2;
    }
}

// ---------- K1: c_bmn = sigmoid(x@Wc^T + bc)/N  (frag-linear operand loads) ----------
__global__ __launch_bounds__(256) void k_cluster(const __bf16* __restrict__ xb,
        const __bf16* __restrict__ Wc, const float* __restrict__ bc,
        __bf16* __restrict__ cbmn) {
    int n0 = blockIdx.x * 128, b = blockIdx.y;
    int t = threadIdx.x, w = t >> 6, l = t & 63, quad = (l >> 4), l16 = l & 15;
    int nt0 = b * 64 + (n0 >> 4);
    f4v acc[2][4];
#pragma unroll
    for (int i = 0; i < 2; i++) for (int j = 0; j < 4; j++) acc[i][j] = (f4v)0.0f;
    for (int kc = 0; kc < 24; kc++) {
        bf8 afr[2], bfr[4];
#pragma unroll
        for (int sr = 0; sr < 2; sr++)
            afr[sr] = *(const bf8*)&xb[((size_t)((nt0 + w * 2 + sr) * 24 + kc)) * 512 + l * 8];
#pragma unroll
        for (int sc = 0; sc < 4; sc++)
            bfr[sc] = *(const bf8*)&Wc[((size_t)(sc * 24 + kc)) * 512 + l * 8];
#pragma unroll
        for (int sr = 0; sr < 2; sr++)
#pragma unroll
            for (int sc = 0; sc < 4; sc++)
                acc[sr][sc] = mfma16(afr[sr], bfr[sc], acc[sr][sc]);
    }
#pragma unroll
    for (int sr = 0; sr < 2; sr++)
#pragma unroll
        for (int sc = 0; sc < 4; sc++) {
            int m = sc * 16 + l16;
            float bias = bc[m];
            bf4 p;
#pragma unroll
            for (int r = 0; r < 4; r++) {
                float val = acc[sr][sc][r] + bias;
                val = 1.0f / (1.0f + __expf(-val));
                p[r] = f2bf(val * (1.0f / 1024.0f));
            }
            *(bf4*)&cbmn[((size_t)(b * MM + m)) * NN + n0 + w * 32 + sr * 16 + quad * 4] = p;
        }
}

// ---------- K2: z[b,m,c] = sum_n c_bmn * xt   (unchanged) ----------
__global__ __launch_bounds__(256) void k_z(const __bf16* __restrict__ cbmn,
        const __bf16* __restrict__ xt, float* __restrict__ z) {
    int c0 = blockIdx.x * 64, b = blockIdx.y;
    int t = threadIdx.x, w = t >> 6, l = t & 63, quad = l >> 4, l16 = l & 15;
    f4v acc[4];
#pragma unroll
    for (int j = 0; j < 4; j++) acc[j] = (f4v)0.0f;
    for (int n0 = 0; n0 < NN; n0 += 32) {
        bf8 afr = *(const bf8*)&cbmn[((size_t)(b * MM + w * 16 + l16)) * NN + n0 + quad * 8];
#pragma unroll
        for (int sc = 0; sc < 4; sc++) {
            bf8 bfr = *(const bf8*)&xt[((size_t)(b * CC + c0 + sc * 16 + l16)) * NN + n0 + quad * 8];
            acc[sc] = mfma16(afr, bfr, acc[sc]);
        }
    }
#pragma unroll
    for (int sc = 0; sc < 4; sc++) {
        int cc = c0 + sc * 16 + l16;
#pragma unroll
        for (int r = 0; r < 4; r++) {
            int m = w * 16 + quad * 4 + r;
            z[((size_t)(b * MM + m)) * CC + cc] = acc[sc][r];
        }
    }
}

// ---------- K2b: L2-normalize rows of z, write bf16 (unchanged) ----------
__global__ __launch_bounds__(256) void k_znorm(const float* __restrict__ z, __bf16* __restrict__ zb) {
    int w = threadIdx.x >> 6, l = threadIdx.x & 63;
    int row = blockIdx.x * 4 + w;
    const float* zr = &z[(size_t)row * CC];
    float v[12]; float ss = 0.f;
#pragma unroll
    for (int i = 0; i < 12; i++) { v[i] = zr[l + i * 64]; ss += v[i] * v[i]; }
#pragma unroll
    for (int off = 32; off; off >>= 1) ss += __shfl_xor(ss, off);
    float s = 1.0f / fmaxf(sqrtf(ss), 1e-12f);
    __bf16* zo = &zb[(size_t)row * CC];
#pragma unroll
    for (int i = 0; i < 12; i++) zo[l + i * 64] = f2bf(v[i] * s);
}

// ---------- K3: k/v projections (unchanged; Wk/Wv row-major) ----------
__global__ __launch_bounds__(256) void k_kv(const __bf16* __restrict__ zb,
        const __bf16* __restrict__ Wk, const float* __restrict__ bk,
        const __bf16* __restrict__ Wv, const float* __restrict__ bv,
        __bf16* __restrict__ kout, __bf16* __restrict__ vtout) {
    int ct = blockIdx.x, b = blockIdx.y, which = blockIdx.z;
    const __bf16* W = which ? Wv : Wk;
    const float* bias = which ? bv : bk;
    int t = threadIdx.x, w = t >> 6, l = t & 63, quad = l >> 4, l16 = l & 15;
    f4v acc[4][2];
#pragma unroll
    for (int i = 0; i < 4; i++) for (int j = 0; j < 2; j++) acc[i][j] = (f4v)0.0f;
    for (int k0 = 0; k0 < CC; k0 += 32) {
        bf8 afr[4], bfr[2];
#pragma unroll
        for (int sr = 0; sr < 4; sr++)
            afr[sr] = *(const bf8*)&zb[((size_t)(b * MM + sr * 16 + l16)) * CC + k0 + quad * 8];
#pragma unroll
        for (int sc = 0; sc < 2; sc++)
            bfr[sc] = *(const bf8*)&W[((size_t)(ct * 128 + w * 32 + sc * 16 + l16)) * CC + k0 + quad * 8];
#pragma unroll
        for (int sr = 0; sr < 4; sr++)
#pragma unroll
            for (int sc = 0; sc < 2; sc++)
                acc[sr][sc] = mfma16(afr[sr], bfr[sc], acc[sr][sc]);
    }
#pragma unroll
    for (int sr = 0; sr < 4; sr++)
#pragma unroll
        for (int sc = 0; sc < 2; sc++) {
            int col = ct * 128 + w * 32 + sc * 16 + l16;
            float bb = bias[col];
            int h = col >> 6, d = col & 63;
            if (which == 0) {
#pragma unroll
                for (int r = 0; r < 4; r++) {
                    int m = sr * 16 + quad * 4 + r;
                    kout[(((size_t)(b * HH + h)) * MM + m) * DD + d] = f2bf(acc[sr][sc][r] + bb);
                }
            } else {
                bf4 p;
#pragma unroll
                for (int r = 0; r < 4; r++) p[r] = f2bf(acc[sr][sc][r] + bb);
                *(bf4*)&vtout[(((size_t)(b * HH + h)) * DD + d) * MM + sr * 16 + quad * 4] = p;
            }
        }
}

// ======== HYBRID 128x256 GEMM: A staged via LDS (frag-linear, depth-3),
//          B double-buffered in REGISTERS (loaded 1 full iteration ahead).
// Per iter: issue B(kt+1) -> ds_read A(kt) -> stage A(kt+2) -> 32 MFMA on
// bcur=B(kt) (latency hidden by the previous iteration) -> vmcnt(6) keeps
// B(kt+1)(4)+stageA(kt+2)(2) in flight while draining stageA(kt+1) -> barrier.
#define STAGE_AF(Asrc, buf, kcs)                                                      \
    do {                                                                              \
        __bf16* _d = (buf);                                                           \
        gl2lds16(&(Asrc)[((size_t)((gt0 + w) * 24 + (kcs))) * 512 + l * 8], &_d[w * 512]); \
        gl2lds16(&(Asrc)[((size_t)((gt0 + w + 4) * 24 + (kcs))) * 512 + l * 8], &_d[(w + 4) * 512]); \
    } while (0)

#define GEMM_KLOOP_H(Asrc, Bsrc)                                                      \
    bf8 bcur[4], bnxt[4];                                                             \
    _Pragma("unroll")                                                                 \
    for (int sc = 0; sc < 4; sc++)                                                    \
        bcur[sc] = *(const bf8*)&(Bsrc)[((size_t)((jt * 16 + w * 4 + sc) * 24)) * 512 + l * 8]; \
    STAGE_AF(Asrc, As3, 0);                                                           \
    STAGE_AF(Asrc, As3 + 4096, 1);                                                    \
    asm volatile("s_waitcnt vmcnt(2)" ::: "memory");                                  \
    __builtin_amdgcn_s_barrier();                                                     \
    for (int kt = 0; kt < 24; ++kt) {                                                 \
        const __bf16* As = As3 + (kt % 3) * 4096;                                     \
        if (kt < 23) {                                                                \
            _Pragma("unroll")                                                         \
            for (int sc = 0; sc < 4; sc++)                                            \
                bnxt[sc] = *(const bf8*)&(Bsrc)[((size_t)((jt * 16 + w * 4 + sc) * 24 + kt + 1)) * 512 + l * 8]; \
        }                                                                             \
        bf8 afr[8];                                                                   \
        _Pragma("unroll")                                                             \
        for (int sr = 0; sr < 8; sr++)                                                \
            afr[sr] = *(const bf8*)&As[sr * 512 + l * 8];                             \
        __builtin_amdgcn_sched_barrier(0);                                            \
        if (kt < 22) STAGE_AF(Asrc, As3 + ((kt + 2) % 3) * 4096, kt + 2);             \
        __builtin_amdgcn_s_setprio(1);                                                \
        _Pragma("unroll")                                                             \
        for (int sr = 0; sr < 8; sr++)                                                \
            _Pragma("unroll")                                                         \
            for (int sc = 0; sc < 4; sc++)                                            \
                acc[sr][sc] = mfma16(afr[sr], bcur[sc], acc[sr][sc]);                 \
        __builtin_amdgcn_s_setprio(0);                                                \
        if (kt < 23) {                                                                \
            _Pragma("unroll")                                                         \
            for (int sc = 0; sc < 4; sc++) bcur[sc] = bnxt[sc];                       \
        }                                                                             \
        if (kt < 22)       asm volatile("s_waitcnt vmcnt(6)" ::: "memory");           \
        else if (kt == 22) asm volatile("s_waitcnt vmcnt(4)" ::: "memory");           \
        __builtin_amdgcn_s_barrier();                                                 \
    }

// ---------- K4: q = xb @ Wq^T + bq -> q FRAG-LINEAR [nt][h][kcs][lane][8] ----------
__global__ __launch_bounds__(256, 2) void k_qproj(const __bf16* __restrict__ xb,
        const __bf16* __restrict__ Wq, const float* __restrict__ bq,
        __bf16* __restrict__ qb) {
    // 768 blocks = 8 XCD x 96 (32 row-stripes x 3 jt per chunk): A-stripe L2-local.
    int orig = blockIdx.x;
    int lid = (orig & 7) * 96 + (orig >> 3);
    int jt = lid % 3;
    int gt0 = (lid / 3) * 8;   // 8 row-tiles = 128 rows

    __shared__ __align__(16) __bf16 As3[3 * 4096];  // 24 KB A triple-buffer
    __shared__ __align__(16) __bf16 eb[128 * 72];   // 18 KB epilogue
    int t = threadIdx.x, w = t >> 6, l = t & 63, quad = l >> 4, l16 = l & 15;
    f4v acc[8][4];
#pragma unroll
    for (int i = 0; i < 8; i++) for (int j = 0; j < 4; j++) acc[i][j] = (f4v)0.0f;

    GEMM_KLOOP_H(xb, Wq);

    // epilogue: 4 phases; phase p: wave p dumps its 128x64 (pad 72); all threads
    // then store frag-linear q for head h = jt*4+p with contiguous 1KB lines.
    for (int p = 0; p < 4; ++p) {
        if (w == p) {
#pragma unroll
            for (int sc = 0; sc < 4; sc++) {
                int col = jt * 256 + p * 64 + sc * 16 + l16;
                float bb = bq[col];
#pragma unroll
                for (int sr = 0; sr < 8; sr++)
#pragma unroll
                    for (int r = 0; r < 4; r++)
                        eb[(sr * 16 + quad * 4 + r) * 72 + sc * 16 + l16] = f2bf(acc[sr][sc][r] + bb);
            }
        }
        __syncthreads();
        int h = jt * 4 + p;
#pragma unroll
        for (int i = 0; i < 4; i++) {
            int idx = t + 256 * i, nt = idx >> 7, kcs = (idx >> 6) & 1, lane = idx & 63;
            bf8 v = *(const bf8*)&eb[(nt * 16 + (lane & 15)) * 72 + kcs * 32 + (lane >> 4) * 8];
            *(bf8*)&qb[((size_t)(((gt0 + nt) * 12 + h) * 2 + kcs)) * 512 + lane * 8] = v;
        }
        __syncthreads();
    }
}

// ---------- K5: attention (q frag-linear in, o frag-linear out; K/V unchanged) ----------
#define QS 72
__global__ __launch_bounds__(256) void k_attn(const __bf16* __restrict__ qb,
        const __bf16* __restrict__ kb, const __bf16* __restrict__ vt,
        __bf16* __restrict__ ob) {
    int n0 = blockIdx.x * 128, h = blockIdx.y, b = blockIdx.z;
    __shared__ __align__(16) __bf16 ps[128 * QS];
    int t = threadIdx.x, w = t >> 6, l = t & 63, quad = l >> 4, l16 = l & 15;
    size_t bh = (size_t)(b * HH + h);
    int nt0 = b * 64 + (n0 >> 4);

    f4v sacc[2][4];
#pragma unroll
    for (int i = 0; i < 2; i++) for (int j = 0; j < 4; j++) sacc[i][j] = (f4v)0.0f;
#pragma unroll
    for (int kc = 0; kc < 2; kc++) {
        bf8 afr[2], bfr[4];
#pragma unroll
        for (int sr = 0; sr < 2; sr++)
            afr[sr] = *(const bf8*)&qb[((size_t)(((nt0 + w * 2 + sr) * 12 + h) * 2 + kc)) * 512 + l * 8];
#pragma unroll
        for (int sc = 0; sc < 4; sc++)
            bfr[sc] = *(const bf8*)&kb[(bh * MM + sc * 16 + l16) * DD + kc * 32 + quad * 8];
#pragma unroll
        for (int sr = 0; sr < 2; sr++)
#pragma unroll
            for (int sc = 0; sc < 4; sc++)
                sacc[sr][sc] = mfma16(afr[sr], bfr[sc], sacc[sr][sc]);
    }
#pragma unroll
    for (int sr = 0; sr < 2; sr++) {
#pragma unroll
        for (int r = 0; r < 4; r++) {
            float mx = -1e30f;
#pragma unroll
            for (int sc = 0; sc < 4; sc++) mx = fmaxf(mx, sacc[sr][sc][r] * 0.125f);
#pragma unroll
            for (int off = 1; off < 16; off <<= 1) mx = fmaxf(mx, __shfl_xor(mx, off));
            float e[4]; float sum = 0.f;
#pragma unroll
            for (int sc = 0; sc < 4; sc++) { e[sc] = __expf(sacc[sr][sc][r] * 0.125f - mx); sum += e[sc]; }
#pragma unroll
            for (int off = 1; off < 16; off <<= 1) sum += __shfl_xor(sum, off);
            float inv = 1.0f / sum;
            int row = w * 32 + sr * 16 + quad * 4 + r;
#pragma unroll
            for (int sc = 0; sc < 4; sc++) ps[row * QS + sc * 16 + l16] = f2bf(e[sc] * inv);
        }
    }
    f4v oacc[2][4];
#pragma unroll
    for (int i = 0; i < 2; i++) for (int j = 0; j < 4; j++) oacc[i][j] = (f4v)0.0f;
#pragma unroll
    for (int kc = 0; kc < 2; kc++) {
        bf8 afr[2], bfr[4];
#pragma unroll
        for (int sr = 0; sr < 2; sr++)
            afr[sr] = *(const bf8*)&ps[(w * 32 + sr * 16 + l16) * QS + kc * 32 + quad * 8];
#pragma unroll
        for (int sc = 0; sc < 4; sc++)
            bfr[sc] = *(const bf8*)&vt[(bh * DD + sc * 16 + l16) * MM + kc * 32 + quad * 8];
#pragma unroll
        for (int sr = 0; sr < 2; sr++)
#pragma unroll
            for (int sc = 0; sc < 4; sc++)
                oacc[sr][sc] = mfma16(afr[sr], bfr[sc], oacc[sr][sc]);
    }
#pragma unroll
    for (int sr = 0; sr < 2; sr++)
#pragma unroll
        for (int sc = 0; sc < 4; sc++) {
            int row = w * 32 + sr * 16;
#pragma unroll
            for (int r = 0; r < 4; r++)
                ps[(row + quad * 4 + r) * QS + sc * 16 + l16] = f2bf(oacc[sr][sc][r]);
        }
    __syncthreads();
#pragma unroll
    for (int i = 0; i < 4; i++) {
        int idx = t + 256 * i, nt = idx >> 7, kcs = (idx >> 6) & 1, lane = idx & 63;
        bf8 v = *(const bf8*)&ps[(nt * 16 + (lane & 15)) * QS + kcs * 32 + (lane >> 4) * 8];
        *(bf8*)&ob[((size_t)((nt0 + nt) * 24 + h * 2 + kcs)) * 512 + lane * 8] = v;
    }
}

// ---------- K6: out = o @ Wp^T + bp  (o frag-linear in, fp32 row-major out) ----------
__global__ __launch_bounds__(256, 2) void k_oproj(const __bf16* __restrict__ ob,
        const __bf16* __restrict__ Wp, const float* __restrict__ bp,
        float* __restrict__ out) {
    int orig = blockIdx.x;
    int lid = (orig & 7) * 96 + (orig >> 3);
    int jt = lid % 3;
    int gt0 = (lid / 3) * 8;
    size_t arow0 = (size_t)(lid / 3) * 128;

    __shared__ __align__(16) __bf16 As3[3 * 4096];  // 24 KB
    __shared__ __align__(16) float ebf[128 * 68];   // 34 KB fp32 epilogue
    int t = threadIdx.x, w = t >> 6, l = t & 63, quad = l >> 4, l16 = l & 15;
    f4v acc[8][4];
#pragma unroll
    for (int i = 0; i < 8; i++) for (int j = 0; j < 4; j++) acc[i][j] = (f4v)0.0f;

    GEMM_KLOOP_H(ob, Wp);

    for (int p = 0; p < 4; ++p) {
        if (w == p) {
#pragma unroll
            for (int sc = 0; sc < 4; sc++) {
                int col = jt * 256 + p * 64 + sc * 16 + l16;
                float bb = bp[col];
#pragma unroll
                for (int sr = 0; sr < 8; sr++)
#pragma unroll
                    for (int r = 0; r < 4; r++)
                        ebf[(sr * 16 + quad * 4 + r) * 68 + sc * 16 + l16] = acc[sr][sc][r] + bb;
            }
        }
        __syncthreads();
#pragma unroll
        for (int i = 0; i < 8; i++) {
            int idx = t + 256 * i, row = idx >> 4, c4 = idx & 15;
            *(float4*)&out[(arow0 + row) * CC + jt * 256 + p * 64 + c4 * 4] = *(const float4*)&ebf[row * 68 + c4 * 4];
        }
        __syncthreads();
    }
}

extern "C" void kernel_launch(void* const* d_in, const int* in_sizes, int n_in,
                              void* d_out, int out_size, void* d_ws, size_t ws_size,
                              hipStream_t stream) {
    (void)in_sizes; (void)n_in; (void)out_size; (void)ws_size;
    const float* x  = (const float*)d_in[0];
    const float* Wc = (const float*)d_in[1];
    const float* bc = (const float*)d_in[2];
    const float* Wq = (const float*)d_in[3];
    const float* bq = (const float*)d_in[4];
    const float* Wk = (const float*)d_in[5];
    const float* bk = (const float*)d_in[6];
    const float* Wv = (const float*)d_in[7];
    const float* bv = (const float*)d_in[8];
    const float* Wp = (const float*)d_in[9];
    const float* bp = (const float*)d_in[10];
    float* out = (float*)d_out;

    char* ws = (char*)d_ws;
    size_t off = 0;
    auto alloc = [&](size_t bytes) { void* p = ws + off; off = (off + bytes + 255) & ~(size_t)255; return p; };
    __bf16* wc_b = (__bf16*)alloc((size_t)MM * CC * 2);
    __bf16* wq_b = (__bf16*)alloc((size_t)CC * CC * 2);
    __bf16* wk_b = (__bf16*)alloc((size_t)CC * CC * 2);
    __bf16* wv_b = (__bf16*)alloc((size_t)CC * CC * 2);
    __bf16* wp_b = (__bf16*)alloc((size_t)CC * CC * 2);
    __bf16* xb   = (__bf16*)alloc((size_t)BB * NN * CC * 2);
    __bf16* xt_o = (__bf16*)alloc((size_t)BB * NN * CC * 2);  // xt, reused as o (frag)
    __bf16* q_b  = (__bf16*)alloc((size_t)BB * NN * CC * 2);
    __bf16* c_bmn= (__bf16*)alloc((size_t)BB * MM * NN * 2);
    float*  z_f  = (float*) alloc((size_t)BB * MM * CC * 4);
    __bf16* z_b  = (__bf16*)alloc((size_t)BB * MM * CC * 2);
    __bf16* k_b  = (__bf16*)alloc((size_t)BB * HH * MM * DD * 2);
    __bf16* v_t  = (__bf16*)alloc((size_t)BB * HH * MM * DD * 2);

    k_cvtW<<<dim3((CC * CC / 4 + 255) / 256, 5), 256, 0, stream>>>(
        Wc, Wq, Wk, Wv, Wp, wc_b, wq_b, wk_b, wv_b, wp_b);

    k_cvtx<<<dim3(CC / 64, NN / 64, BB), 256, 0, stream>>>(x, xb, xt_o);
    k_cluster<<<dim3(NN / 128, BB), 256, 0, stream>>>(xb, wc_b, bc, c_bmn);
    k_z<<<dim3(CC / 64, BB), 256, 0, stream>>>(c_bmn, xt_o, z_f);
    k_znorm<<<(BB * MM) / 4, 256, 0, stream>>>(z_f, z_b);
    k_kv<<<dim3(CC / 128, BB, 2), 256, 0, stream>>>(z_b, wk_b, bk, wv_b, bv, k_b, v_t);
    k_qproj<<<dim3((BB * NN / 128) * 3), 256, 0, stream>>>(xb, wq_b, bq, q_b);
    k_attn<<<dim3(NN / 128, HH, BB), 256, 0, stream>>>(q_b, k_b, v_t, xt_o /* o reuses xt */);
    k_oproj<<<dim3((BB * NN / 128) * 3), 256, 0, stream>>>(xt_o, wp_b, bp, out);
}

// Round 10
// 265.733 us; speedup vs baseline: 1.1850x; 1.0006x over previous
//
#include <hip/hip_runtime.h>
#include <hip/hip_bf16.h>
#include <cstdint>

// ---- problem constants ----
#define BB 32
#define NN 1024
#define CC 768
#define MM 64
#define HH 12
#define DD 64

typedef float f4v __attribute__((ext_vector_type(4)));
typedef __bf16 bf8 __attribute__((ext_vector_type(8)));
typedef __bf16 bf4 __attribute__((ext_vector_type(4)));

__device__ __forceinline__ f4v mfma16(bf8 a, bf8 b, f4v c) {
    return __builtin_amdgcn_mfma_f32_16x16x32_bf16(a, b, c, 0, 0, 0);
}
__device__ __forceinline__ __bf16 f2bf(float f) { return (__bf16)f; }

__device__ __forceinline__ void gl2lds16(const void* g, void* lds) {
    __builtin_amdgcn_global_load_lds((const __attribute__((address_space(1))) void*)g,
                                     (__attribute__((address_space(3))) void*)lds, 16, 0, 0);
}

// ================= fragment-linear layout (lane-order) =================
// frag[tile16][kc32][lane64][8]: element (row, k) at
//   tile = row>>4, kc = k>>5, LANE = ((k>>3)&3)*16 + (row&15), e = k&7
// A wave's fragment load = base + l*8 -> one coalesced 1KB line; lane l gets
// exactly its MFMA fragment element. Staged blocks stay lane-ordered in LDS ->
// ds_read at base+l*16B is stride-1 across the wave: conflict-free, no swizzle.

// ---------- all weights fp32 -> bf16; Wc/Wq/Wp FRAG-LINEAR, Wk/Wv row-major ----------
__global__ __launch_bounds__(256) void k_cvtW(
        const float* __restrict__ Wc, const float* __restrict__ Wq,
        const float* __restrict__ Wk, const float* __restrict__ Wv,
        const float* __restrict__ Wp,
        __bf16* __restrict__ wc, __bf16* __restrict__ wq,
        __bf16* __restrict__ wk, __bf16* __restrict__ wv,
        __bf16* __restrict__ wp) {
    const float* in; __bf16* out; int n4; int frag;
    switch (blockIdx.y) {
        case 0: in = Wc; out = wc; n4 = MM * CC / 4; frag = 1; break;
        case 1: in = Wq; out = wq; n4 = CC * CC / 4; frag = 1; break;
        case 2: in = Wk; out = wk; n4 = CC * CC / 4; frag = 0; break;
        case 3: in = Wv; out = wv; n4 = CC * CC / 4; frag = 0; break;
        default: in = Wp; out = wp; n4 = CC * CC / 4; frag = 1; break;
    }
    int i = blockIdx.x * 256 + threadIdx.x;
    if (i < n4) {
        float4 v = *(const float4*)&in[i * 4];
        bf4 o; o[0] = f2bf(v.x); o[1] = f2bf(v.y); o[2] = f2bf(v.z); o[3] = f2bf(v.w);
        if (frag) {
            int lin = i * 4, m = lin / CC, c = lin % CC;
            size_t off = ((size_t)((m >> 4) * 24 + (c >> 5))) * 512
                       + ((((c >> 3) & 3) * 16) + (m & 15)) * 8 + (c & 7);
            *(bf4*)&out[off] = o;
        } else {
            *(bf4*)&out[i * 4] = o;
        }
    }
}

// ---------- K0: x -> xb FRAG-LINEAR (via LDS, full 1KB-line stores)
//                AND xt (b,c,n) row-major via padded LDS transpose ----------
// tileR [64][72] row-major: phase-1 bf4 vector writes (conflict-free phases);
//   phase-2a reads each (nt,kc) fragment block in lane order (stride-144B rows
//   step 4 banks per row -> conflict-free b128 phases) and stores ONE contiguous
//   1KB line per wave -> no partial-line write-allocate RMW (was 4x 8B scatter).
// tileT [64][66] transposed: unchanged from R9 (passed; conflicts modest).
__global__ __launch_bounds__(256) void k_cvtx(const float* __restrict__ x,
        __bf16* __restrict__ xb, __bf16* __restrict__ xt) {
    int c0 = blockIdx.x * 64, n0 = blockIdx.y * 64, b = blockIdx.z;
    __shared__ __align__(16) __bf16 tileT[64 * 66];
    __shared__ __align__(16) __bf16 tileR[64 * 72];
    int t = threadIdx.x;
#pragma unroll
    for (int i = 0; i < 4; i++) {
        int idx = t + 256 * i, r = idx >> 4, cq = idx & 15;
        float4 v = *(const float4*)&x[((size_t)(b * NN + n0 + r)) * CC + c0 + cq * 4];
        float vv[4] = {v.x, v.y, v.z, v.w};
        bf4 o;
#pragma unroll
        for (int j = 0; j < 4; j++) {
            __bf16 bv = f2bf(vv[j]);
            o[j] = bv;
            tileT[(cq * 4 + j) * 66 + r] = bv;
        }
        *(bf4*)&tileR[r * 72 + cq * 4] = o;
    }
    __syncthreads();
    // phase 2a: xb frag-linear, 2 rounds; wave = one (nt,kc) block -> 1KB line
    int gnt = b * 64 + (n0 >> 4);
    int kc0 = c0 >> 5;
    int lane = t & 63;
#pragma unroll
    for (int i = 0; i < 2; i++) {
        int idx = t + 256 * i;
        int nt_loc = idx >> 7, kc_loc = (idx >> 6) & 1;
        int row = nt_loc * 16 + (lane & 15);
        int col = kc_loc * 32 + (lane >> 4) * 8;
        bf8 v = *(const bf8*)&tileR[row * 72 + col];
        *(bf8*)&xb[((size_t)((gnt + nt_loc) * 24 + kc0 + kc_loc)) * 512 + lane * 8] = v;
    }
    // phase 2b: xt full-line stores (unchanged)
#pragma unroll
    for (int i = 0; i < 2; i++) {
        int idx = t + 256 * i, c = idx >> 3, ch = idx & 7;
        bf8 v2 = *(const bf8*)&tileT[c * 66 + ch * 8];
        *(bf8*)&xt[((size_t)(b * CC + c0 + c)) * NN + n0 + ch * 8] = v2;
    }
}

// ---------- K1: c_bmn = sigmoid(x@Wc^T + bc)/N  (frag-linear operand loads) ----------
__global__ __launch_bounds__(256) void k_cluster(const __bf16* __restrict__ xb,
        const __bf16* __restrict__ Wc, const float* __restrict__ bc,
        __bf16* __restrict__ cbmn) {
    int n0 = blockIdx.x * 128, b = blockIdx.y;
    int t = threadIdx.x, w = t >> 6, l = t & 63, quad = (l >> 4), l16 = l & 15;
    int nt0 = b * 64 + (n0 >> 4);
    f4v acc[2][4];
#pragma unroll
    for (int i = 0; i < 2; i++) for (int j = 0; j < 4; j++) acc[i][j] = (f4v)0.0f;
    for (int kc = 0; kc < 24; kc++) {
        bf8 afr[2], bfr[4];
#pragma unroll
        for (int sr = 0; sr < 2; sr++)
            afr[sr] = *(const bf8*)&xb[((size_t)((nt0 + w * 2 + sr) * 24 + kc)) * 512 + l * 8];
#pragma unroll
        for (int sc = 0; sc < 4; sc++)
            bfr[sc] = *(const bf8*)&Wc[((size_t)(sc * 24 + kc)) * 512 + l * 8];
#pragma unroll
        for (int sr = 0; sr < 2; sr++)
#pragma unroll
            for (int sc = 0; sc < 4; sc++)
                acc[sr][sc] = mfma16(afr[sr], bfr[sc], acc[sr][sc]);
    }
#pragma unroll
    for (int sr = 0; sr < 2; sr++)
#pragma unroll
        for (int sc = 0; sc < 4; sc++) {
            int m = sc * 16 + l16;
            float bias = bc[m];
            bf4 p;
#pragma unroll
            for (int r = 0; r < 4; r++) {
                float val = acc[sr][sc][r] + bias;
                val = 1.0f / (1.0f + __expf(-val));
                p[r] = f2bf(val * (1.0f / 1024.0f));
            }
            *(bf4*)&cbmn[((size_t)(b * MM + m)) * NN + n0 + w * 32 + sr * 16 + quad * 4] = p;
        }
}

// ---------- K2: z[b,m,c] = sum_n c_bmn * xt   (unchanged) ----------
__global__ __launch_bounds__(256) void k_z(const __bf16* __restrict__ cbmn,
        const __bf16* __restrict__ xt, float* __restrict__ z) {
    int c0 = blockIdx.x * 64, b = blockIdx.y;
    int t = threadIdx.x, w = t >> 6, l = t & 63, quad = l >> 4, l16 = l & 15;
    f4v acc[4];
#pragma unroll
    for (int j = 0; j < 4; j++) acc[j] = (f4v)0.0f;
    for (int n0 = 0; n0 < NN; n0 += 32) {
        bf8 afr = *(const bf8*)&cbmn[((size_t)(b * MM + w * 16 + l16)) * NN + n0 + quad * 8];
#pragma unroll
        for (int sc = 0; sc < 4; sc++) {
            bf8 bfr = *(const bf8*)&xt[((size_t)(b * CC + c0 + sc * 16 + l16)) * NN + n0 + quad * 8];
            acc[sc] = mfma16(afr, bfr, acc[sc]);
        }
    }
#pragma unroll
    for (int sc = 0; sc < 4; sc++) {
        int cc = c0 + sc * 16 + l16;
#pragma unroll
        for (int r = 0; r < 4; r++) {
            int m = w * 16 + quad * 4 + r;
            z[((size_t)(b * MM + m)) * CC + cc] = acc[sc][r];
        }
    }
}

// ---------- K2b: L2-normalize rows of z, write bf16 (unchanged) ----------
__global__ __launch_bounds__(256) void k_znorm(const float* __restrict__ z, __bf16* __restrict__ zb) {
    int w = threadIdx.x >> 6, l = threadIdx.x & 63;
    int row = blockIdx.x * 4 + w;
    const float* zr = &z[(size_t)row * CC];
    float v[12]; float ss = 0.f;
#pragma unroll
    for (int i = 0; i < 12; i++) { v[i] = zr[l + i * 64]; ss += v[i] * v[i]; }
#pragma unroll
    for (int off = 32; off; off >>= 1) ss += __shfl_xor(ss, off);
    float s = 1.0f / fmaxf(sqrtf(ss), 1e-12f);
    __bf16* zo = &zb[(size_t)row * CC];
#pragma unroll
    for (int i = 0; i < 12; i++) zo[l + i * 64] = f2bf(v[i] * s);
}

// ---------- K3: k/v projections (unchanged; Wk/Wv row-major) ----------
__global__ __launch_bounds__(256) void k_kv(const __bf16* __restrict__ zb,
        const __bf16* __restrict__ Wk, const float* __restrict__ bk,
        const __bf16* __restrict__ Wv, const float* __restrict__ bv,
        __bf16* __restrict__ kout, __bf16* __restrict__ vtout) {
    int ct = blockIdx.x, b = blockIdx.y, which = blockIdx.z;
    const __bf16* W = which ? Wv : Wk;
    const float* bias = which ? bv : bk;
    int t = threadIdx.x, w = t >> 6, l = t & 63, quad = l >> 4, l16 = l & 15;
    f4v acc[4][2];
#pragma unroll
    for (int i = 0; i < 4; i++) for (int j = 0; j < 2; j++) acc[i][j] = (f4v)0.0f;
    for (int k0 = 0; k0 < CC; k0 += 32) {
        bf8 afr[4], bfr[2];
#pragma unroll
        for (int sr = 0; sr < 4; sr++)
            afr[sr] = *(const bf8*)&zb[((size_t)(b * MM + sr * 16 + l16)) * CC + k0 + quad * 8];
#pragma unroll
        for (int sc = 0; sc < 2; sc++)
            bfr[sc] = *(const bf8*)&W[((size_t)(ct * 128 + w * 32 + sc * 16 + l16)) * CC + k0 + quad * 8];
#pragma unroll
        for (int sr = 0; sr < 4; sr++)
#pragma unroll
            for (int sc = 0; sc < 2; sc++)
                acc[sr][sc] = mfma16(afr[sr], bfr[sc], acc[sr][sc]);
    }
#pragma unroll
    for (int sr = 0; sr < 4; sr++)
#pragma unroll
        for (int sc = 0; sc < 2; sc++) {
            int col = ct * 128 + w * 32 + sc * 16 + l16;
            float bb = bias[col];
            int h = col >> 6, d = col & 63;
            if (which == 0) {
#pragma unroll
                for (int r = 0; r < 4; r++) {
                    int m = sr * 16 + quad * 4 + r;
                    kout[(((size_t)(b * HH + h)) * MM + m) * DD + d] = f2bf(acc[sr][sc][r] + bb);
                }
            } else {
                bf4 p;
#pragma unroll
                for (int r = 0; r < 4; r++) p[r] = f2bf(acc[sr][sc][r] + bb);
                *(bf4*)&vtout[(((size_t)(b * HH + h)) * DD + d) * MM + sr * 16 + quad * 4] = p;
            }
        }
}

// ======== HYBRID 128x256 GEMM: A staged via LDS (frag-linear, depth-3),
//          B double-buffered in REGISTERS (loaded 1 full iteration ahead).
// Per iter: issue B(kt+1) -> ds_read A(kt) -> stage A(kt+2) -> 32 MFMA on
// bcur=B(kt) (latency hidden by the previous iteration) -> vmcnt(6) keeps
// B(kt+1)(4)+stageA(kt+2)(2) in flight while draining stageA(kt+1) -> barrier.
#define STAGE_AF(Asrc, buf, kcs)                                                      \
    do {                                                                              \
        __bf16* _d = (buf);                                                           \
        gl2lds16(&(Asrc)[((size_t)((gt0 + w) * 24 + (kcs))) * 512 + l * 8], &_d[w * 512]); \
        gl2lds16(&(Asrc)[((size_t)((gt0 + w + 4) * 24 + (kcs))) * 512 + l * 8], &_d[(w + 4) * 512]); \
    } while (0)

#define GEMM_KLOOP_H(Asrc, Bsrc)                                                      \
    bf8 bcur[4], bnxt[4];                                                             \
    _Pragma("unroll")                                                                 \
    for (int sc = 0; sc < 4; sc++)                                                    \
        bcur[sc] = *(const bf8*)&(Bsrc)[((size_t)((jt * 16 + w * 4 + sc) * 24)) * 512 + l * 8]; \
    STAGE_AF(Asrc, As3, 0);                                                           \
    STAGE_AF(Asrc, As3 + 4096, 1);                                                    \
    asm volatile("s_waitcnt vmcnt(2)" ::: "memory");                                  \
    __builtin_amdgcn_s_barrier();                                                     \
    for (int kt = 0; kt < 24; ++kt) {                                                 \
        const __bf16* As = As3 + (kt % 3) * 4096;                                     \
        if (kt < 23) {                                                                \
            _Pragma("unroll")                                                         \
            for (int sc = 0; sc < 4; sc++)                                            \
                bnxt[sc] = *(const bf8*)&(Bsrc)[((size_t)((jt * 16 + w * 4 + sc) * 24 + kt + 1)) * 512 + l * 8]; \
        }                                                                             \
        bf8 afr[8];                                                                   \
        _Pragma("unroll")                                                             \
        for (int sr = 0; sr < 8; sr++)                                                \
            afr[sr] = *(const bf8*)&As[sr * 512 + l * 8];                             \
        __builtin_amdgcn_sched_barrier(0);                                            \
        if (kt < 22) STAGE_AF(Asrc, As3 + ((kt + 2) % 3) * 4096, kt + 2);             \
        __builtin_amdgcn_s_setprio(1);                                                \
        _Pragma("unroll")                                                             \
        for (int sr = 0; sr < 8; sr++)                                                \
            _Pragma("unroll")                                                         \
            for (int sc = 0; sc < 4; sc++)                                            \
                acc[sr][sc] = mfma16(afr[sr], bcur[sc], acc[sr][sc]);                 \
        __builtin_amdgcn_s_setprio(0);                                                \
        if (kt < 23) {                                                                \
            _Pragma("unroll")                                                         \
            for (int sc = 0; sc < 4; sc++) bcur[sc] = bnxt[sc];                       \
        }                                                                             \
        if (kt < 22)       asm volatile("s_waitcnt vmcnt(6)" ::: "memory");           \
        else if (kt == 22) asm volatile("s_waitcnt vmcnt(4)" ::: "memory");           \
        __builtin_amdgcn_s_barrier();                                                 \
    }

// ---------- K4: q = xb @ Wq^T + bq -> q FRAG-LINEAR [nt][h][kcs][lane][8] ----------
__global__ __launch_bounds__(256, 2) void k_qproj(const __bf16* __restrict__ xb,
        const __bf16* __restrict__ Wq, const float* __restrict__ bq,
        __bf16* __restrict__ qb) {
    // 768 blocks = 8 XCD x 96 (32 row-stripes x 3 jt per chunk): A-stripe L2-local.
    int orig = blockIdx.x;
    int lid = (orig & 7) * 96 + (orig >> 3);
    int jt = lid % 3;
    int gt0 = (lid / 3) * 8;   // 8 row-tiles = 128 rows

    __shared__ __align__(16) __bf16 As3[3 * 4096];  // 24 KB A triple-buffer
    __shared__ __align__(16) __bf16 eb[128 * 72];   // 18 KB epilogue
    int t = threadIdx.x, w = t >> 6, l = t & 63, quad = l >> 4, l16 = l & 15;
    f4v acc[8][4];
#pragma unroll
    for (int i = 0; i < 8; i++) for (int j = 0; j < 4; j++) acc[i][j] = (f4v)0.0f;

    GEMM_KLOOP_H(xb, Wq);

    // epilogue: 4 phases; phase p: wave p dumps its 128x64 (pad 72); all threads
    // then store frag-linear q for head h = jt*4+p with contiguous 1KB lines.
    for (int p = 0; p < 4; ++p) {
        if (w == p) {
#pragma unroll
            for (int sc = 0; sc < 4; sc++) {
                int col = jt * 256 + p * 64 + sc * 16 + l16;
                float bb = bq[col];
#pragma unroll
                for (int sr = 0; sr < 8; sr++)
#pragma unroll
                    for (int r = 0; r < 4; r++)
                        eb[(sr * 16 + quad * 4 + r) * 72 + sc * 16 + l16] = f2bf(acc[sr][sc][r] + bb);
            }
        }
        __syncthreads();
        int h = jt * 4 + p;
#pragma unroll
        for (int i = 0; i < 4; i++) {
            int idx = t + 256 * i, nt = idx >> 7, kcs = (idx >> 6) & 1, lane = idx & 63;
            bf8 v = *(const bf8*)&eb[(nt * 16 + (lane & 15)) * 72 + kcs * 32 + (lane >> 4) * 8];
            *(bf8*)&qb[((size_t)(((gt0 + nt) * 12 + h) * 2 + kcs)) * 512 + lane * 8] = v;
        }
        __syncthreads();
    }
}

// ---------- K5: attention (q frag-linear in, o frag-linear out; K/V unchanged) ----------
#define QS 72
__global__ __launch_bounds__(256) void k_attn(const __bf16* __restrict__ qb,
        const __bf16* __restrict__ kb, const __bf16* __restrict__ vt,
        __bf16* __restrict__ ob) {
    int n0 = blockIdx.x * 128, h = blockIdx.y, b = blockIdx.z;
    __shared__ __align__(16) __bf16 ps[128 * QS];
    int t = threadIdx.x, w = t >> 6, l = t & 63, quad = l >> 4, l16 = l & 15;
    size_t bh = (size_t)(b * HH + h);
    int nt0 = b * 64 + (n0 >> 4);

    f4v sacc[2][4];
#pragma unroll
    for (int i = 0; i < 2; i++) for (int j = 0; j < 4; j++) sacc[i][j] = (f4v)0.0f;
#pragma unroll
    for (int kc = 0; kc < 2; kc++) {
        bf8 afr[2], bfr[4];
#pragma unroll
        for (int sr = 0; sr < 2; sr++)
            afr[sr] = *(const bf8*)&qb[((size_t)(((nt0 + w * 2 + sr) * 12 + h) * 2 + kc)) * 512 + l * 8];
#pragma unroll
        for (int sc = 0; sc < 4; sc++)
            bfr[sc] = *(const bf8*)&kb[(bh * MM + sc * 16 + l16) * DD + kc * 32 + quad * 8];
#pragma unroll
        for (int sr = 0; sr < 2; sr++)
#pragma unroll
            for (int sc = 0; sc < 4; sc++)
                sacc[sr][sc] = mfma16(afr[sr], bfr[sc], sacc[sr][sc]);
    }
#pragma unroll
    for (int sr = 0; sr < 2; sr++) {
#pragma unroll
        for (int r = 0; r < 4; r++) {
            float mx = -1e30f;
#pragma unroll
            for (int sc = 0; sc < 4; sc++) mx = fmaxf(mx, sacc[sr][sc][r] * 0.125f);
#pragma unroll
            for (int off = 1; off < 16; off <<= 1) mx = fmaxf(mx, __shfl_xor(mx, off));
            float e[4]; float sum = 0.f;
#pragma unroll
            for (int sc = 0; sc < 4; sc++) { e[sc] = __expf(sacc[sr][sc][r] * 0.125f - mx); sum += e[sc]; }
#pragma unroll
            for (int off = 1; off < 16; off <<= 1) sum += __shfl_xor(sum, off);
            float inv = 1.0f / sum;
            int row = w * 32 + sr * 16 + quad * 4 + r;
#pragma unroll
            for (int sc = 0; sc < 4; sc++) ps[row * QS + sc * 16 + l16] = f2bf(e[sc] * inv);
        }
    }
    f4v oacc[2][4];
#pragma unroll
    for (int i = 0; i < 2; i++) for (int j = 0; j < 4; j++) oacc[i][j] = (f4v)0.0f;
#pragma unroll
    for (int kc = 0; kc < 2; kc++) {
        bf8 afr[2], bfr[4];
#pragma unroll
        for (int sr = 0; sr < 2; sr++)
            afr[sr] = *(const bf8*)&ps[(w * 32 + sr * 16 + l16) * QS + kc * 32 + quad * 8];
#pragma unroll
        for (int sc = 0; sc < 4; sc++)
            bfr[sc] = *(const bf8*)&vt[(bh * DD + sc * 16 + l16) * MM + kc * 32 + quad * 8];
#pragma unroll
        for (int sr = 0; sr < 2; sr++)
#pragma unroll
            for (int sc = 0; sc < 4; sc++)
                oacc[sr][sc] = mfma16(afr[sr], bfr[sc], oacc[sr][sc]);
    }
#pragma unroll
    for (int sr = 0; sr < 2; sr++)
#pragma unroll
        for (int sc = 0; sc < 4; sc++) {
            int row = w * 32 + sr * 16;
#pragma unroll
            for (int r = 0; r < 4; r++)
                ps[(row + quad * 4 + r) * QS + sc * 16 + l16] = f2bf(oacc[sr][sc][r]);
        }
    __syncthreads();
#pragma unroll
    for (int i = 0; i < 4; i++) {
        int idx = t + 256 * i, nt = idx >> 7, kcs = (idx >> 6) & 1, lane = idx & 63;
        bf8 v = *(const bf8*)&ps[(nt * 16 + (lane & 15)) * QS + kcs * 32 + (lane >> 4) * 8];
        *(bf8*)&ob[((size_t)((nt0 + nt) * 24 + h * 2 + kcs)) * 512 + lane * 8] = v;
    }
}

// ---------- K6: out = o @ Wp^T + bp  (o frag-linear in, fp32 row-major out) ----------
__global__ __launch_bounds__(256, 2) void k_oproj(const __bf16* __restrict__ ob,
        const __bf16* __restrict__ Wp, const float* __restrict__ bp,
        float* __restrict__ out) {
    int orig = blockIdx.x;
    int lid = (orig & 7) * 96 + (orig >> 3);
    int jt = lid % 3;
    int gt0 = (lid / 3) * 8;
    size_t arow0 = (size_t)(lid / 3) * 128;

    __shared__ __align__(16) __bf16 As3[3 * 4096];  // 24 KB
    __shared__ __align__(16) float ebf[128 * 68];   // 34 KB fp32 epilogue
    int t = threadIdx.x, w = t >> 6, l = t & 63, quad = l >> 4, l16 = l & 15;
    f4v acc[8][4];
#pragma unroll
    for (int i = 0; i < 8; i++) for (int j = 0; j < 4; j++) acc[i][j] = (f4v)0.0f;

    GEMM_KLOOP_H(ob, Wp);

    for (int p = 0; p < 4; ++p) {
        if (w == p) {
#pragma unroll
            for (int sc = 0; sc < 4; sc++) {
                int col = jt * 256 + p * 64 + sc * 16 + l16;
                float bb = bp[col];
#pragma unroll
                for (int sr = 0; sr < 8; sr++)
#pragma unroll
                    for (int r = 0; r < 4; r++)
                        ebf[(sr * 16 + quad * 4 + r) * 68 + sc * 16 + l16] = acc[sr][sc][r] + bb;
            }
        }
        __syncthreads();
#pragma unroll
        for (int i = 0; i < 8; i++) {
            int idx = t + 256 * i, row = idx >> 4, c4 = idx & 15;
            *(float4*)&out[(arow0 + row) * CC + jt * 256 + p * 64 + c4 * 4] = *(const float4*)&ebf[row * 68 + c4 * 4];
        }
        __syncthreads();
    }
}

extern "C" void kernel_launch(void* const* d_in, const int* in_sizes, int n_in,
                              void* d_out, int out_size, void* d_ws, size_t ws_size,
                              hipStream_t stream) {
    (void)in_sizes; (void)n_in; (void)out_size; (void)ws_size;
    const float* x  = (const float*)d_in[0];
    const float* Wc = (const float*)d_in[1];
    const float* bc = (const float*)d_in[2];
    const float* Wq = (const float*)d_in[3];
    const float* bq = (const float*)d_in[4];
    const float* Wk = (const float*)d_in[5];
    const float* bk = (const float*)d_in[6];
    const float* Wv = (const float*)d_in[7];
    const float* bv = (const float*)d_in[8];
    const float* Wp = (const float*)d_in[9];
    const float* bp = (const float*)d_in[10];
    float* out = (float*)d_out;

    char* ws = (char*)d_ws;
    size_t off = 0;
    auto alloc = [&](size_t bytes) { void* p = ws + off; off = (off + bytes + 255) & ~(size_t)255; return p; };
    __bf16* wc_b = (__bf16*)alloc((size_t)MM * CC * 2);
    __bf16* wq_b = (__bf16*)alloc((size_t)CC * CC * 2);
    __bf16* wk_b = (__bf16*)alloc((size_t)CC * CC * 2);
    __bf16* wv_b = (__bf16*)alloc((size_t)CC * CC * 2);
    __bf16* wp_b = (__bf16*)alloc((size_t)CC * CC * 2);
    __bf16* xb   = (__bf16*)alloc((size_t)BB * NN * CC * 2);
    __bf16* xt_o = (__bf16*)alloc((size_t)BB * NN * CC * 2);  // xt, reused as o (frag)
    __bf16* q_b  = (__bf16*)alloc((size_t)BB * NN * CC * 2);
    __bf16* c_bmn= (__bf16*)alloc((size_t)BB * MM * NN * 2);
    float*  z_f  = (float*) alloc((size_t)BB * MM * CC * 4);
    __bf16* z_b  = (__bf16*)alloc((size_t)BB * MM * CC * 2);
    __bf16* k_b  = (__bf16*)alloc((size_t)BB * HH * MM * DD * 2);
    __bf16* v_t  = (__bf16*)alloc((size_t)BB * HH * MM * DD * 2);

    k_cvtW<<<dim3((CC * CC / 4 + 255) / 256, 5), 256, 0, stream>>>(
        Wc, Wq, Wk, Wv, Wp, wc_b, wq_b, wk_b, wv_b, wp_b);

    k_cvtx<<<dim3(CC / 64, NN / 64, BB), 256, 0, stream>>>(x, xb, xt_o);
    k_cluster<<<dim3(NN / 128, BB), 256, 0, stream>>>(xb, wc_b, bc, c_bmn);
    k_z<<<dim3(CC / 64, BB), 256, 0, stream>>>(c_bmn, xt_o, z_f);
    k_znorm<<<(BB * MM) / 4, 256, 0, stream>>>(z_f, z_b);
    k_kv<<<dim3(CC / 128, BB, 2), 256, 0, stream>>>(z_b, wk_b, bk, wv_b, bv, k_b, v_t);
    k_qproj<<<dim3((BB * NN / 128) * 3), 256, 0, stream>>>(xb, wq_b, bq, q_b);
    k_attn<<<dim3(NN / 128, HH, BB), 256, 0, stream>>>(q_b, k_b, v_t, xt_o /* o reuses xt */);
    k_oproj<<<dim3((BB * NN / 128) * 3), 256, 0, stream>>>(xt_o, wp_b, bp, out);
}